// Round 1
// baseline (335.232 us; speedup 1.0000x reference)
//
#include <hip/hip_runtime.h>

typedef __bf16 bf16_t;
typedef __bf16 bf16x8 __attribute__((ext_vector_type(8)));
typedef __bf16 bf16x4 __attribute__((ext_vector_type(4)));
typedef float  floatx4 __attribute__((ext_vector_type(4)));

#define BM 128
#define BN 128
#define BK 32

// async global->LDS, 16B per lane. LDS dest must be wave-uniform base + lane*16.
__device__ __forceinline__ void gld_lds16(const bf16_t* g, bf16_t* l) {
  __builtin_amdgcn_global_load_lds(
      (__attribute__((address_space(1))) const void*)g,
      (__attribute__((address_space(3))) void*)l, 16, 0, 0);
}

// C[128x128] = A[M,K] @ Bt[N,K]^T tile. 256 threads = 4 waves in 2x2.
// Each wave: 64x64 via 4x4 mfma_f32_16x16x32_bf16.
__device__ __forceinline__ void gemm_bt_core(
    const bf16_t* __restrict__ A, int lda,
    const bf16_t* __restrict__ Bt, int ldb,
    int rowBase, int colBase, int kTiles,
    bf16_t* ldsA, bf16_t* ldsB, floatx4 acc[4][4])
{
  const int t    = threadIdx.x;
  const int lane = t & 63;
  const int wave = t >> 6;
  const int wy   = wave >> 1;
  const int wx   = wave & 1;
  const int quad = lane >> 4;
  const int r16  = lane & 15;

  // staging addresses: each thread covers 16B (8 bf16); 256 thr * 16B = 64 rows/issue
  const bf16_t* ga = A  + (size_t)(rowBase + (t >> 2)) * lda + (t & 3) * 8;
  const bf16_t* gb = Bt + (size_t)(colBase + (t >> 2)) * ldb + (t & 3) * 8;
  bf16_t* la = ldsA + t * 8;   // byte offset t*16 == wave_base + lane*16
  bf16_t* lb = ldsB + t * 8;

#pragma unroll
  for (int i = 0; i < 4; ++i)
#pragma unroll
    for (int j = 0; j < 4; ++j)
      acc[i][j] = (floatx4){0.f, 0.f, 0.f, 0.f};

  for (int kt = 0; kt < kTiles; ++kt) {
    const int k0 = kt * BK;
    gld_lds16(ga + k0,                    la);
    gld_lds16(ga + k0 + (size_t)64 * lda, la + 64 * BK);
    gld_lds16(gb + k0,                    lb);
    gld_lds16(gb + k0 + (size_t)64 * ldb, lb + 64 * BK);
    __syncthreads();   // drains vmcnt (global_load_lds) + barrier

    bf16x8 af[4], bfr[4];
#pragma unroll
    for (int i = 0; i < 4; ++i)
      af[i] = *(const bf16x8*)(ldsA + (wy * 64 + i * 16 + r16) * BK + quad * 8);
#pragma unroll
    for (int j = 0; j < 4; ++j)
      bfr[j] = *(const bf16x8*)(ldsB + (wx * 64 + j * 16 + r16) * BK + quad * 8);
#pragma unroll
    for (int i = 0; i < 4; ++i)
#pragma unroll
      for (int j = 0; j < 4; ++j)
        acc[i][j] = __builtin_amdgcn_mfma_f32_16x16x32_bf16(af[i], bfr[j], acc[i][j], 0, 0, 0);
    __syncthreads();   // protect LDS before next stage
  }
}

// epilogue index helpers (C/D layout: col = lane&15, row = (lane>>4)*4 + reg)
#define EPILOGUE_SETUP()                       \
  const int t    = threadIdx.x;                \
  const int lane = t & 63;                     \
  const int wave = t >> 6;                     \
  const int wy   = wave >> 1;                  \
  const int wx   = wave & 1;                   \
  const int quad = lane >> 4;                  \
  const int r16  = lane & 15;

// ---------------- conversion / transpose kernels ----------------

__global__ void __launch_bounds__(256) k_cvt_bf16(const float* __restrict__ in,
                                                  bf16_t* __restrict__ out) {
  const size_t idx = (size_t)blockIdx.x * 256 + threadIdx.x;
  float4 v = ((const float4*)in)[idx];
  bf16x4 o;
  o[0] = (bf16_t)v.x; o[1] = (bf16_t)v.y; o[2] = (bf16_t)v.z; o[3] = (bf16_t)v.w;
  ((bf16x4*)out)[idx] = o;
}

// in [R][C] fp32 -> out [C][R] bf16.  grid (C/32, R/32), block (32,8)
__global__ void __launch_bounds__(256) k_transpose_cvt(const float* __restrict__ in,
                                                       bf16_t* __restrict__ out,
                                                       int R, int C) {
  __shared__ float tile[32][33];
  const int tx = threadIdx.x;
  const int ty = threadIdx.y;
  const int c0 = blockIdx.x * 32;
  const int r0 = blockIdx.y * 32;
#pragma unroll
  for (int rr = 0; rr < 32; rr += 8)
    tile[ty + rr][tx] = in[(size_t)(r0 + ty + rr) * C + (c0 + tx)];
  __syncthreads();
#pragma unroll
  for (int cc = 0; cc < 32; cc += 8)
    out[(size_t)(c0 + ty + cc) * R + (r0 + tx)] = (bf16_t)tile[tx][ty + cc];
}

// ---------------- GEMM kernels ----------------

// QKV: C[8192,3072] = Xb[8192,1024] @ Wqkv_t[3072,1024]^T ; scatter q/k/v_t bf16
__global__ void __launch_bounds__(256) k_gemm_qkv(
    const bf16_t* __restrict__ X, const bf16_t* __restrict__ Wt,
    bf16_t* __restrict__ Q, bf16_t* __restrict__ Kmat, bf16_t* __restrict__ Vt) {
  __shared__ bf16_t ldsA[BM * BK];
  __shared__ bf16_t ldsB[BN * BK];
  floatx4 acc[4][4];
  const int rowBase = blockIdx.y * BM;
  const int colBase = blockIdx.x * BN;
  gemm_bt_core(X, 1024, Wt, 1024, rowBase, colBase, 1024 / BK, ldsA, ldsB, acc);
  EPILOGUE_SETUP();
#pragma unroll
  for (int i = 0; i < 4; ++i) {
    const int m0 = rowBase + wy * 64 + i * 16 + quad * 4;
#pragma unroll
    for (int j = 0; j < 4; ++j) {
      const int n = colBase + wx * 64 + j * 16 + r16;
#pragma unroll
      for (int rr = 0; rr < 4; ++rr) {
        const int m = m0 + rr;
        const float v = acc[i][j][rr];
        if (n < 1024) {
          Q[(size_t)m * 1024 + n] = (bf16_t)v;
        } else if (n < 2048) {
          Kmat[(size_t)m * 1024 + (n - 1024)] = (bf16_t)v;
        } else {
          const int b = m >> 11, s = m & 2047;
          Vt[(size_t)b * (1024 * 2048) + (size_t)(n - 2048) * 2048 + s] = (bf16_t)v;
        }
      }
    }
  }
}

// QK^T per batch: Sim[b][2048][2048] fp32 (lower-triangular blocks only)
__global__ void __launch_bounds__(256) k_gemm_qk(
    const bf16_t* __restrict__ Q, const bf16_t* __restrict__ Kmat,
    float* __restrict__ Sim) {
  const int bx = blockIdx.x, by = blockIdx.y, b = blockIdx.z;
  if (bx > by) return;  // fully-masked block
  __shared__ bf16_t ldsA[BM * BK];
  __shared__ bf16_t ldsB[BN * BK];
  floatx4 acc[4][4];
  const bf16_t* Ab = Q + (size_t)b * 2048 * 1024;
  const bf16_t* Bb = Kmat + (size_t)b * 2048 * 1024;
  const int rowBase = by * BM, colBase = bx * BN;
  gemm_bt_core(Ab, 1024, Bb, 1024, rowBase, colBase, 1024 / BK, ldsA, ldsB, acc);
  float* C = Sim + (size_t)b * 2048 * 2048;
  EPILOGUE_SETUP();
#pragma unroll
  for (int i = 0; i < 4; ++i) {
    const int m0 = rowBase + wy * 64 + i * 16 + quad * 4;
#pragma unroll
    for (int j = 0; j < 4; ++j) {
      const int n = colBase + wx * 64 + j * 16 + r16;
#pragma unroll
      for (int rr = 0; rr < 4; ++rr)
        C[(size_t)(m0 + rr) * 2048 + n] = acc[i][j][rr];
    }
  }
}

// causal softmax per row; Sim fp32 -> P bf16; zero-fill masked tail of the row's
// 128-block so PV can consume whole K-tiles.
__global__ void __launch_bounds__(256) k_softmax(const float* __restrict__ Sim,
                                                 bf16_t* __restrict__ P) {
  const int rid = blockIdx.x;      // b*2048 + i
  const int i = rid & 2047;
  const int tid = threadIdx.x;
  const int lane = tid & 63, wave = tid >> 6;
  const float* srow = Sim + (size_t)rid * 2048;
  bf16_t* prow = P + (size_t)rid * 2048;
  const int L = i + 1;
  const float scale = 0.03125f;    // 1024^-0.5

  float vals[8];
  float lm = -1e30f;
#pragma unroll
  for (int tq = 0; tq < 8; ++tq) {
    const int j = tq * 256 + tid;
    const float v = (j < L) ? srow[j] * scale : -1e30f;
    vals[tq] = v;
    lm = fmaxf(lm, v);
  }
  __shared__ float red[8];
#pragma unroll
  for (int off = 32; off > 0; off >>= 1) lm = fmaxf(lm, __shfl_xor(lm, off, 64));
  if (lane == 0) red[wave] = lm;
  __syncthreads();
  const float gm = fmaxf(fmaxf(red[0], red[1]), fmaxf(red[2], red[3]));

  float ev[8];
  float ls = 0.f;
#pragma unroll
  for (int tq = 0; tq < 8; ++tq) {
    ev[tq] = __expf(vals[tq] - gm);   // masked lanes: exp(-1e30) == 0
    ls += ev[tq];
  }
#pragma unroll
  for (int off = 32; off > 0; off >>= 1) ls += __shfl_xor(ls, off, 64);
  if (lane == 0) red[4 + wave] = ls;
  __syncthreads();
  const float gs = red[4] + red[5] + red[6] + red[7];
  const float inv = 1.0f / gs;

  const int upper = ((i >> 7) + 1) << 7;
#pragma unroll
  for (int tq = 0; tq < 8; ++tq) {
    const int j = tq * 256 + tid;
    if (j < L)          prow[j] = (bf16_t)(ev[tq] * inv);
    else if (j < upper) prow[j] = (bf16_t)0.f;
  }
}

// PV per batch: O[b][2048][1024] bf16 = P[b] @ Vt[b]^T, K-loop bounded causally
__global__ void __launch_bounds__(256) k_gemm_pv(
    const bf16_t* __restrict__ P, const bf16_t* __restrict__ Vt,
    bf16_t* __restrict__ O) {
  const int bx = blockIdx.x, by = blockIdx.y, b = blockIdx.z;
  __shared__ bf16_t ldsA[BM * BK];
  __shared__ bf16_t ldsB[BN * BK];
  floatx4 acc[4][4];
  const bf16_t* Ab = P + (size_t)b * 2048 * 2048;
  const bf16_t* Bb = Vt + (size_t)b * 1024 * 2048;
  const int rowBase = by * BM, colBase = bx * BN;
  gemm_bt_core(Ab, 2048, Bb, 2048, rowBase, colBase, (by + 1) * 4, ldsA, ldsB, acc);
  bf16_t* C = O + (size_t)b * 2048 * 1024;
  EPILOGUE_SETUP();
#pragma unroll
  for (int i = 0; i < 4; ++i) {
    const int m0 = rowBase + wy * 64 + i * 16 + quad * 4;
#pragma unroll
    for (int j = 0; j < 4; ++j) {
      const int n = colBase + wx * 64 + j * 16 + r16;
#pragma unroll
      for (int rr = 0; rr < 4; ++rr)
        C[(size_t)(m0 + rr) * 1024 + n] = (bf16_t)acc[i][j][rr];
    }
  }
}

// out-proj: out[8192,1024] fp32 = O[8192,1024] @ Wout_t[1024,1024]^T + bias
__global__ void __launch_bounds__(256) k_gemm_out(
    const bf16_t* __restrict__ O, const bf16_t* __restrict__ Wt,
    const float* __restrict__ bias, float* __restrict__ out) {
  __shared__ bf16_t ldsA[BM * BK];
  __shared__ bf16_t ldsB[BN * BK];
  floatx4 acc[4][4];
  const int rowBase = blockIdx.y * BM;
  const int colBase = blockIdx.x * BN;
  gemm_bt_core(O, 1024, Wt, 1024, rowBase, colBase, 1024 / BK, ldsA, ldsB, acc);
  EPILOGUE_SETUP();
#pragma unroll
  for (int i = 0; i < 4; ++i) {
    const int m0 = rowBase + wy * 64 + i * 16 + quad * 4;
#pragma unroll
    for (int j = 0; j < 4; ++j) {
      const int n = colBase + wx * 64 + j * 16 + r16;
      const float bb = bias[n];
#pragma unroll
      for (int rr = 0; rr < 4; ++rr)
        out[(size_t)(m0 + rr) * 1024 + n] = acc[i][j][rr] + bb;
    }
  }
}

// ---------------- launch ----------------
// ws layout (bytes):
//   xb    @ 0          16,777,216   x as bf16 [8192,1024]
//   wqkvt @ 16777216    6,291,456   w_qkv^T bf16 [3072,1024]
//   woutt @ 23068672    2,097,152   w_out^T bf16 [1024,1024]
//   q     @ 25165824   16,777,216   [b,s,1024] bf16
//   k     @ 41943040   16,777,216   [b,s,1024] bf16
//   vt    @ 58720256   16,777,216   [b,1024,s] bf16 (V transposed)
//   sim   @ 75497472   67,108,864   [b,s,s] fp32 (lower-tri blocks only)
//   p     @ 142606336  33,554,432   [b,s,s] bf16
//   o     @ 176160768  16,777,216   [b,s,1024] bf16
// total 192,937,984 B
extern "C" void kernel_launch(void* const* d_in, const int* in_sizes, int n_in,
                              void* d_out, int out_size, void* d_ws, size_t ws_size,
                              hipStream_t stream) {
  const float* x     = (const float*)d_in[0];
  const float* w_qkv = (const float*)d_in[1];
  const float* w_out = (const float*)d_in[2];
  const float* b_out = (const float*)d_in[3];
  float* out = (float*)d_out;
  char* ws = (char*)d_ws;

  bf16_t* xb   = (bf16_t*)(ws + 0);
  bf16_t* wqt  = (bf16_t*)(ws + 16777216);
  bf16_t* wot  = (bf16_t*)(ws + 23068672);
  bf16_t* q    = (bf16_t*)(ws + 25165824);
  bf16_t* kmat = (bf16_t*)(ws + 41943040);
  bf16_t* vt   = (bf16_t*)(ws + 58720256);
  float*  sim  = (float*)(ws + 75497472);
  bf16_t* p    = (bf16_t*)(ws + 142606336);
  bf16_t* o    = (bf16_t*)(ws + 176160768);

  k_cvt_bf16<<<8192, 256, 0, stream>>>(x, xb);                       // 8.4M elems /4
  k_transpose_cvt<<<dim3(96, 32), dim3(32, 8), 0, stream>>>(w_qkv, wqt, 1024, 3072);
  k_transpose_cvt<<<dim3(32, 32), dim3(32, 8), 0, stream>>>(w_out, wot, 1024, 1024);
  k_gemm_qkv<<<dim3(24, 64), 256, 0, stream>>>(xb, wqt, q, kmat, vt);
  k_gemm_qk<<<dim3(16, 16, 4), 256, 0, stream>>>(q, kmat, sim);
  k_softmax<<<8192, 256, 0, stream>>>(sim, p);
  k_gemm_pv<<<dim3(8, 16, 4), 256, 0, stream>>>(p, vt, o);
  k_gemm_out<<<dim3(8, 64), 256, 0, stream>>>(o, wot, b_out, out);
}

// Round 2
// 311.435 us; speedup vs baseline: 1.0764x; 1.0764x over previous
//
#include <hip/hip_runtime.h>

typedef __bf16 bf16_t;
typedef __bf16 bf16x8 __attribute__((ext_vector_type(8)));
typedef __bf16 bf16x4 __attribute__((ext_vector_type(4)));
typedef float  floatx4 __attribute__((ext_vector_type(4)));

#define BM 128
#define BN 128
#define BK 32

// async global->LDS, 16B per lane. LDS dest must be wave-uniform base + lane*16.
__device__ __forceinline__ void gld_lds16(const bf16_t* g, bf16_t* l) {
  __builtin_amdgcn_global_load_lds(
      (__attribute__((address_space(1))) const void*)g,
      (__attribute__((address_space(3))) void*)l, 16, 0, 0);
}

// C[128x128] = A[M,K] @ Bt[N,K]^T tile. 256 threads = 4 waves in 2x2.
// Each wave: 64x64 via 4x4 mfma_f32_16x16x32_bf16.
__device__ __forceinline__ void gemm_bt_core(
    const bf16_t* __restrict__ A, int lda,
    const bf16_t* __restrict__ Bt, int ldb,
    int rowBase, int colBase, int kTiles,
    bf16_t* ldsA, bf16_t* ldsB, floatx4 acc[4][4])
{
  const int t    = threadIdx.x;
  const int lane = t & 63;
  const int wave = t >> 6;
  const int wy   = wave >> 1;
  const int wx   = wave & 1;
  const int quad = lane >> 4;
  const int r16  = lane & 15;

  // staging addresses: each thread covers 16B (8 bf16); 256 thr * 16B = 64 rows/issue
  const bf16_t* ga = A  + (size_t)(rowBase + (t >> 2)) * lda + (t & 3) * 8;
  const bf16_t* gb = Bt + (size_t)(colBase + (t >> 2)) * ldb + (t & 3) * 8;
  bf16_t* la = ldsA + t * 8;   // byte offset t*16 == wave_base + lane*16
  bf16_t* lb = ldsB + t * 8;

#pragma unroll
  for (int i = 0; i < 4; ++i)
#pragma unroll
    for (int j = 0; j < 4; ++j)
      acc[i][j] = (floatx4){0.f, 0.f, 0.f, 0.f};

  for (int kt = 0; kt < kTiles; ++kt) {
    const int k0 = kt * BK;
    gld_lds16(ga + k0,                    la);
    gld_lds16(ga + k0 + (size_t)64 * lda, la + 64 * BK);
    gld_lds16(gb + k0,                    lb);
    gld_lds16(gb + k0 + (size_t)64 * ldb, lb + 64 * BK);
    __syncthreads();   // drains vmcnt (global_load_lds) + barrier

    bf16x8 af[4], bfr[4];
#pragma unroll
    for (int i = 0; i < 4; ++i)
      af[i] = *(const bf16x8*)(ldsA + (wy * 64 + i * 16 + r16) * BK + quad * 8);
#pragma unroll
    for (int j = 0; j < 4; ++j)
      bfr[j] = *(const bf16x8*)(ldsB + (wx * 64 + j * 16 + r16) * BK + quad * 8);
#pragma unroll
    for (int i = 0; i < 4; ++i)
#pragma unroll
      for (int j = 0; j < 4; ++j)
        acc[i][j] = __builtin_amdgcn_mfma_f32_16x16x32_bf16(af[i], bfr[j], acc[i][j], 0, 0, 0);
    __syncthreads();   // protect LDS before next stage
  }
}

// epilogue index helpers (C/D layout: col = lane&15, row = (lane>>4)*4 + reg)
#define EPILOGUE_SETUP()                       \
  const int t    = threadIdx.x;                \
  const int lane = t & 63;                     \
  const int wave = t >> 6;                     \
  const int wy   = wave >> 1;                  \
  const int wx   = wave & 1;                   \
  const int quad = lane >> 4;                  \
  const int r16  = lane & 15;

// ---------------- conversion / transpose kernels ----------------

__global__ void __launch_bounds__(256) k_cvt_bf16(const float* __restrict__ in,
                                                  bf16_t* __restrict__ out) {
  const size_t idx = (size_t)blockIdx.x * 256 + threadIdx.x;
  float4 v = ((const float4*)in)[idx];
  bf16x4 o;
  o[0] = (bf16_t)v.x; o[1] = (bf16_t)v.y; o[2] = (bf16_t)v.z; o[3] = (bf16_t)v.w;
  ((bf16x4*)out)[idx] = o;
}

// in [R][C] fp32 -> out [C][R] bf16.  grid (C/32, R/32), block (32,8)
__global__ void __launch_bounds__(256) k_transpose_cvt(const float* __restrict__ in,
                                                       bf16_t* __restrict__ out,
                                                       int R, int C) {
  __shared__ float tile[32][33];
  const int tx = threadIdx.x;
  const int ty = threadIdx.y;
  const int c0 = blockIdx.x * 32;
  const int r0 = blockIdx.y * 32;
#pragma unroll
  for (int rr = 0; rr < 32; rr += 8)
    tile[ty + rr][tx] = in[(size_t)(r0 + ty + rr) * C + (c0 + tx)];
  __syncthreads();
#pragma unroll
  for (int cc = 0; cc < 32; cc += 8)
    out[(size_t)(c0 + ty + cc) * R + (r0 + tx)] = (bf16_t)tile[tx][ty + cc];
}

// ---------------- GEMM kernels ----------------

// QKV: C[8192,3072] = Xb[8192,1024] @ Wqkv_t[3072,1024]^T ; scatter q/k/v_t bf16
// Block-uniform epilogue: colBase 0..895 -> Q (scaled by 2^-5), 1024.. -> K,
// 2048.. -> V^T (vectorized bf16x4 along s).
__global__ void __launch_bounds__(256) k_gemm_qkv(
    const bf16_t* __restrict__ X, const bf16_t* __restrict__ Wt,
    bf16_t* __restrict__ Q, bf16_t* __restrict__ Kmat, bf16_t* __restrict__ Vt) {
  __shared__ bf16_t ldsA[BM * BK];
  __shared__ bf16_t ldsB[BN * BK];
  floatx4 acc[4][4];
  const int rowBase = blockIdx.y * BM;
  const int colBase = blockIdx.x * BN;
  gemm_bt_core(X, 1024, Wt, 1024, rowBase, colBase, 1024 / BK, ldsA, ldsB, acc);
  EPILOGUE_SETUP();
  if (colBase < 1024) {
    // Q region: fold softmax scale 1024^-0.5 = 2^-5 (exact in bf16)
#pragma unroll
    for (int i = 0; i < 4; ++i) {
      const int m0 = rowBase + wy * 64 + i * 16 + quad * 4;
#pragma unroll
      for (int j = 0; j < 4; ++j) {
        const int n = colBase + wx * 64 + j * 16 + r16;
#pragma unroll
        for (int rr = 0; rr < 4; ++rr)
          Q[(size_t)(m0 + rr) * 1024 + n] = (bf16_t)(acc[i][j][rr] * 0.03125f);
      }
    }
  } else if (colBase < 2048) {
    const int nb = colBase - 1024;
#pragma unroll
    for (int i = 0; i < 4; ++i) {
      const int m0 = rowBase + wy * 64 + i * 16 + quad * 4;
#pragma unroll
      for (int j = 0; j < 4; ++j) {
        const int n = nb + wx * 64 + j * 16 + r16;
#pragma unroll
        for (int rr = 0; rr < 4; ++rr)
          Kmat[(size_t)(m0 + rr) * 1024 + n] = (bf16_t)acc[i][j][rr];
      }
    }
  } else {
    const int nb = colBase - 2048;
    const int b = rowBase >> 11;            // 128-aligned rows: whole block same batch
#pragma unroll
    for (int i = 0; i < 4; ++i) {
      const int m0 = rowBase + wy * 64 + i * 16 + quad * 4;
      const int s0 = m0 & 2047;
#pragma unroll
      for (int j = 0; j < 4; ++j) {
        const int n = nb + wx * 64 + j * 16 + r16;
        bf16x4 pk;
#pragma unroll
        for (int rr = 0; rr < 4; ++rr) pk[rr] = (bf16_t)acc[i][j][rr];
        *(bf16x4*)(Vt + (size_t)(b * 1024 + n) * 2048 + s0) = pk;
      }
    }
  }
}

// QK^T per batch: Sim[b][2048][2048] fp32 (lower-triangular blocks only)
__global__ void __launch_bounds__(256) k_gemm_qk(
    const bf16_t* __restrict__ Q, const bf16_t* __restrict__ Kmat,
    float* __restrict__ Sim) {
  const int bx = blockIdx.x, by = blockIdx.y, b = blockIdx.z;
  if (bx > by) return;  // fully-masked block
  __shared__ bf16_t ldsA[BM * BK];
  __shared__ bf16_t ldsB[BN * BK];
  floatx4 acc[4][4];
  const bf16_t* Ab = Q + (size_t)b * 2048 * 1024;
  const bf16_t* Bb = Kmat + (size_t)b * 2048 * 1024;
  const int rowBase = by * BM, colBase = bx * BN;
  gemm_bt_core(Ab, 1024, Bb, 1024, rowBase, colBase, 1024 / BK, ldsA, ldsB, acc);
  float* C = Sim + (size_t)b * 2048 * 2048;
  EPILOGUE_SETUP();
#pragma unroll
  for (int i = 0; i < 4; ++i) {
    const int m0 = rowBase + wy * 64 + i * 16 + quad * 4;
#pragma unroll
    for (int j = 0; j < 4; ++j) {
      const int n = colBase + wx * 64 + j * 16 + r16;
#pragma unroll
      for (int rr = 0; rr < 4; ++rr)
        C[(size_t)(m0 + rr) * 2048 + n] = acc[i][j][rr];
    }
  }
}

// causal softmax per row; Sim fp32 -> P bf16; zero-fill masked tail of the row's
// 128-block so PV can consume whole K-tiles. Scale already folded into Q.
__global__ void __launch_bounds__(256) k_softmax(const float* __restrict__ Sim,
                                                 bf16_t* __restrict__ P) {
  const int rid = blockIdx.x;      // b*2048 + i
  const int i = rid & 2047;
  const int tid = threadIdx.x;
  const int lane = tid & 63, wave = tid >> 6;
  const float* srow = Sim + (size_t)rid * 2048;
  bf16_t* prow = P + (size_t)rid * 2048;
  const int L = i + 1;

  float vals[8];
  float lm = -1e30f;
#pragma unroll
  for (int tq = 0; tq < 8; ++tq) {
    const int j = tq * 256 + tid;
    const float v = (j < L) ? srow[j] : -1e30f;
    vals[tq] = v;
    lm = fmaxf(lm, v);
  }
  __shared__ float red[8];
#pragma unroll
  for (int off = 32; off > 0; off >>= 1) lm = fmaxf(lm, __shfl_xor(lm, off, 64));
  if (lane == 0) red[wave] = lm;
  __syncthreads();
  const float gm = fmaxf(fmaxf(red[0], red[1]), fmaxf(red[2], red[3]));

  float ev[8];
  float ls = 0.f;
#pragma unroll
  for (int tq = 0; tq < 8; ++tq) {
    ev[tq] = __expf(vals[tq] - gm);   // masked lanes: exp(-1e30) == 0
    ls += ev[tq];
  }
#pragma unroll
  for (int off = 32; off > 0; off >>= 1) ls += __shfl_xor(ls, off, 64);
  if (lane == 0) red[4 + wave] = ls;
  __syncthreads();
  const float gs = red[4] + red[5] + red[6] + red[7];
  const float inv = 1.0f / gs;

  const int upper = ((i >> 7) + 1) << 7;
#pragma unroll
  for (int tq = 0; tq < 8; ++tq) {
    const int j = tq * 256 + tid;
    if (j < L)          prow[j] = (bf16_t)(ev[tq] * inv);
    else if (j < upper) prow[j] = (bf16_t)0.f;
  }
}

// PV per batch: O[b][2048][1024] bf16 = P[b] @ Vt[b]^T, K-loop bounded causally.
// Heavy-blocks-first remap: by = 15 - blockIdx.y so the 64-iter blocks start first.
__global__ void __launch_bounds__(256) k_gemm_pv(
    const bf16_t* __restrict__ P, const bf16_t* __restrict__ Vt,
    bf16_t* __restrict__ O) {
  const int bx = blockIdx.x, by = 15 - blockIdx.y, b = blockIdx.z;
  __shared__ bf16_t ldsA[BM * BK];
  __shared__ bf16_t ldsB[BN * BK];
  floatx4 acc[4][4];
  const bf16_t* Ab = P + (size_t)b * 2048 * 2048;
  const bf16_t* Bb = Vt + (size_t)b * 1024 * 2048;
  const int rowBase = by * BM, colBase = bx * BN;
  gemm_bt_core(Ab, 2048, Bb, 2048, rowBase, colBase, (by + 1) * 4, ldsA, ldsB, acc);
  bf16_t* C = O + (size_t)b * 2048 * 1024;
  EPILOGUE_SETUP();
#pragma unroll
  for (int i = 0; i < 4; ++i) {
    const int m0 = rowBase + wy * 64 + i * 16 + quad * 4;
#pragma unroll
    for (int j = 0; j < 4; ++j) {
      const int n = colBase + wx * 64 + j * 16 + r16;
#pragma unroll
      for (int rr = 0; rr < 4; ++rr)
        C[(size_t)(m0 + rr) * 1024 + n] = (bf16_t)acc[i][j][rr];
    }
  }
}

// out-proj: out[8192,1024] fp32 = O[8192,1024] @ Wout_t[1024,1024]^T + bias
__global__ void __launch_bounds__(256) k_gemm_out(
    const bf16_t* __restrict__ O, const bf16_t* __restrict__ Wt,
    const float* __restrict__ bias, float* __restrict__ out) {
  __shared__ bf16_t ldsA[BM * BK];
  __shared__ bf16_t ldsB[BN * BK];
  floatx4 acc[4][4];
  const int rowBase = blockIdx.y * BM;
  const int colBase = blockIdx.x * BN;
  gemm_bt_core(O, 1024, Wt, 1024, rowBase, colBase, 1024 / BK, ldsA, ldsB, acc);
  EPILOGUE_SETUP();
#pragma unroll
  for (int i = 0; i < 4; ++i) {
    const int m0 = rowBase + wy * 64 + i * 16 + quad * 4;
#pragma unroll
    for (int j = 0; j < 4; ++j) {
      const int n = colBase + wx * 64 + j * 16 + r16;
      const float bb = bias[n];
#pragma unroll
      for (int rr = 0; rr < 4; ++rr)
        out[(size_t)(m0 + rr) * 1024 + n] = acc[i][j][rr] + bb;
    }
  }
}

// ---------------- launch ----------------
// ws layout (bytes):
//   xb    @ 0          16,777,216   x as bf16 [8192,1024]
//   wqkvt @ 16777216    6,291,456   w_qkv^T bf16 [3072,1024]
//   woutt @ 23068672    2,097,152   w_out^T bf16 [1024,1024]
//   q     @ 25165824   16,777,216   [b,s,1024] bf16 (pre-scaled by 2^-5)
//   k     @ 41943040   16,777,216   [b,s,1024] bf16
//   vt    @ 58720256   16,777,216   [b,1024,s] bf16 (V transposed)
//   sim   @ 75497472   67,108,864   [b,s,s] fp32 (lower-tri blocks only)
//   p     @ 142606336  33,554,432   [b,s,s] bf16
//   o     @ 176160768  16,777,216   [b,s,1024] bf16
// total 192,937,984 B
extern "C" void kernel_launch(void* const* d_in, const int* in_sizes, int n_in,
                              void* d_out, int out_size, void* d_ws, size_t ws_size,
                              hipStream_t stream) {
  const float* x     = (const float*)d_in[0];
  const float* w_qkv = (const float*)d_in[1];
  const float* w_out = (const float*)d_in[2];
  const float* b_out = (const float*)d_in[3];
  float* out = (float*)d_out;
  char* ws = (char*)d_ws;

  bf16_t* xb   = (bf16_t*)(ws + 0);
  bf16_t* wqt  = (bf16_t*)(ws + 16777216);
  bf16_t* wot  = (bf16_t*)(ws + 23068672);
  bf16_t* q    = (bf16_t*)(ws + 25165824);
  bf16_t* kmat = (bf16_t*)(ws + 41943040);
  bf16_t* vt   = (bf16_t*)(ws + 58720256);
  float*  sim  = (float*)(ws + 75497472);
  bf16_t* p    = (bf16_t*)(ws + 142606336);
  bf16_t* o    = (bf16_t*)(ws + 176160768);

  k_cvt_bf16<<<8192, 256, 0, stream>>>(x, xb);                       // 8.4M elems /4
  k_transpose_cvt<<<dim3(96, 32), dim3(32, 8), 0, stream>>>(w_qkv, wqt, 1024, 3072);
  k_transpose_cvt<<<dim3(32, 32), dim3(32, 8), 0, stream>>>(w_out, wot, 1024, 1024);
  k_gemm_qkv<<<dim3(24, 64), 256, 0, stream>>>(xb, wqt, q, kmat, vt);
  k_gemm_qk<<<dim3(16, 16, 4), 256, 0, stream>>>(q, kmat, sim);
  k_softmax<<<8192, 256, 0, stream>>>(sim, p);
  k_gemm_pv<<<dim3(8, 16, 4), 256, 0, stream>>>(p, vt, o);
  k_gemm_out<<<dim3(8, 64), 256, 0, stream>>>(o, wot, b_out, out);
}

// Round 3
// 286.543 us; speedup vs baseline: 1.1699x; 1.0869x over previous
//
#include <hip/hip_runtime.h>

typedef __bf16 bf16_t;
typedef __bf16 bf16x8 __attribute__((ext_vector_type(8)));
typedef __bf16 bf16x4 __attribute__((ext_vector_type(4)));
typedef float  floatx4 __attribute__((ext_vector_type(4)));

#define BM 128
#define BN 128
#define BK 32

// async global->LDS, 16B per lane. LDS dest must be wave-uniform base + lane*16.
__device__ __forceinline__ void gld_lds16(const bf16_t* g, bf16_t* l) {
  __builtin_amdgcn_global_load_lds(
      (__attribute__((address_space(1))) const void*)g,
      (__attribute__((address_space(3))) void*)l, 16, 0, 0);
}

// C[128x128] = A[M,K] @ Bt[N,K]^T tile. 256 threads = 4 waves in 2x2.
__device__ __forceinline__ void gemm_bt_core(
    const bf16_t* __restrict__ A, int lda,
    const bf16_t* __restrict__ Bt, int ldb,
    int rowBase, int colBase, int kTiles,
    bf16_t* ldsA, bf16_t* ldsB, floatx4 acc[4][4])
{
  const int t    = threadIdx.x;
  const int lane = t & 63;
  const int wave = t >> 6;
  const int wy   = wave >> 1;
  const int wx   = wave & 1;
  const int quad = lane >> 4;
  const int r16  = lane & 15;

  const bf16_t* ga = A  + (size_t)(rowBase + (t >> 2)) * lda + (t & 3) * 8;
  const bf16_t* gb = Bt + (size_t)(colBase + (t >> 2)) * ldb + (t & 3) * 8;
  bf16_t* la = ldsA + t * 8;
  bf16_t* lb = ldsB + t * 8;

#pragma unroll
  for (int i = 0; i < 4; ++i)
#pragma unroll
    for (int j = 0; j < 4; ++j)
      acc[i][j] = (floatx4){0.f, 0.f, 0.f, 0.f};

  for (int kt = 0; kt < kTiles; ++kt) {
    const int k0 = kt * BK;
    gld_lds16(ga + k0,                    la);
    gld_lds16(ga + k0 + (size_t)64 * lda, la + 64 * BK);
    gld_lds16(gb + k0,                    lb);
    gld_lds16(gb + k0 + (size_t)64 * ldb, lb + 64 * BK);
    __syncthreads();

    bf16x8 af[4], bfr[4];
#pragma unroll
    for (int i = 0; i < 4; ++i)
      af[i] = *(const bf16x8*)(ldsA + (wy * 64 + i * 16 + r16) * BK + quad * 8);
#pragma unroll
    for (int j = 0; j < 4; ++j)
      bfr[j] = *(const bf16x8*)(ldsB + (wx * 64 + j * 16 + r16) * BK + quad * 8);
#pragma unroll
    for (int i = 0; i < 4; ++i)
#pragma unroll
      for (int j = 0; j < 4; ++j)
        acc[i][j] = __builtin_amdgcn_mfma_f32_16x16x32_bf16(af[i], bfr[j], acc[i][j], 0, 0, 0);
    __syncthreads();
  }
}

#define EPILOGUE_SETUP()                       \
  const int t    = threadIdx.x;                \
  const int lane = t & 63;                     \
  const int wave = t >> 6;                     \
  const int wy   = wave >> 1;                  \
  const int wx   = wave & 1;                   \
  const int quad = lane >> 4;                  \
  const int r16  = lane & 15;

// ---------------- conversion / transpose kernels ----------------

// also zero-inits the rowsum accumulator (blocks 0..31 cover 8192 floats)
__global__ void __launch_bounds__(256) k_cvt_bf16(const float* __restrict__ in,
                                                  bf16_t* __restrict__ out,
                                                  float* __restrict__ rowsum) {
  const size_t idx = (size_t)blockIdx.x * 256 + threadIdx.x;
  if (blockIdx.x < 32) rowsum[idx] = 0.0f;
  float4 v = ((const float4*)in)[idx];
  bf16x4 o;
  o[0] = (bf16_t)v.x; o[1] = (bf16_t)v.y; o[2] = (bf16_t)v.z; o[3] = (bf16_t)v.w;
  ((bf16x4*)out)[idx] = o;
}

// merged transpose: bx<96 -> w_qkv [1024,3072], else w_out [1024,1024]
__global__ void __launch_bounds__(256) k_transpose_cvt(
    const float* __restrict__ in0, bf16_t* __restrict__ out0,
    const float* __restrict__ in1, bf16_t* __restrict__ out1) {
  __shared__ float tile[32][33];
  const int tx = threadIdx.x;
  const int ty = threadIdx.y;
  const bool first = blockIdx.x < 96;
  const float* in = first ? in0 : in1;
  bf16_t* out = first ? out0 : out1;
  const int C = first ? 3072 : 1024;
  const int c0 = (first ? blockIdx.x : blockIdx.x - 96) * 32;
  const int r0 = blockIdx.y * 32;
  const int R = 1024;
#pragma unroll
  for (int rr = 0; rr < 32; rr += 8)
    tile[ty + rr][tx] = in[(size_t)(r0 + ty + rr) * C + (c0 + tx)];
  __syncthreads();
#pragma unroll
  for (int cc = 0; cc < 32; cc += 8)
    out[(size_t)(c0 + ty + cc) * R + (r0 + tx)] = (bf16_t)tile[tx][ty + cc];
}

// ---------------- GEMM kernels ----------------

// QKV: C[8192,3072] = Xb @ Wqkv_t^T ; scatter q (pre-scaled 2^-5) / k / v_t.
// Grid swizzled into 8-row super-bands for L2 locality on B.
__global__ void __launch_bounds__(256) k_gemm_qkv(
    const bf16_t* __restrict__ X, const bf16_t* __restrict__ Wt,
    bf16_t* __restrict__ Q, bf16_t* __restrict__ Kmat, bf16_t* __restrict__ Vt) {
  __shared__ bf16_t ldsA[BM * BK];
  __shared__ bf16_t ldsB[BN * BK];
  floatx4 acc[4][4];
  const int lin = blockIdx.y * 24 + blockIdx.x;
  const int st = lin / 192, r = lin % 192;
  const int by = st * 8 + (r & 7);
  const int bx = r >> 3;
  const int rowBase = by * BM;
  const int colBase = bx * BN;
  gemm_bt_core(X, 1024, Wt, 1024, rowBase, colBase, 1024 / BK, ldsA, ldsB, acc);
  EPILOGUE_SETUP();
  if (colBase < 1024) {
#pragma unroll
    for (int i = 0; i < 4; ++i) {
      const int m0 = rowBase + wy * 64 + i * 16 + quad * 4;
#pragma unroll
      for (int j = 0; j < 4; ++j) {
        const int n = colBase + wx * 64 + j * 16 + r16;
#pragma unroll
        for (int rr = 0; rr < 4; ++rr)
          Q[(size_t)(m0 + rr) * 1024 + n] = (bf16_t)(acc[i][j][rr] * 0.03125f);
      }
    }
  } else if (colBase < 2048) {
    const int nb = colBase - 1024;
#pragma unroll
    for (int i = 0; i < 4; ++i) {
      const int m0 = rowBase + wy * 64 + i * 16 + quad * 4;
#pragma unroll
      for (int j = 0; j < 4; ++j) {
        const int n = nb + wx * 64 + j * 16 + r16;
#pragma unroll
        for (int rr = 0; rr < 4; ++rr)
          Kmat[(size_t)(m0 + rr) * 1024 + n] = (bf16_t)acc[i][j][rr];
      }
    }
  } else {
    const int nb = colBase - 2048;
    const int b = rowBase >> 11;
#pragma unroll
    for (int i = 0; i < 4; ++i) {
      const int m0 = rowBase + wy * 64 + i * 16 + quad * 4;
      const int s0 = m0 & 2047;
#pragma unroll
      for (int j = 0; j < 4; ++j) {
        const int n = nb + wx * 64 + j * 16 + r16;
        bf16x4 pk;
#pragma unroll
        for (int rr = 0; rr < 4; ++rr) pk[rr] = (bf16_t)acc[i][j][rr];
        *(bf16x4*)(Vt + (size_t)(b * 1024 + n) * 2048 + s0) = pk;
      }
    }
  }
}

// QK^T + exp fused. Q pre-scaled so acc == logit. No max-subtraction needed:
// logits ~ N(0,1), |logit| << 88. Writes p_unnorm bf16 (masked -> 0) and
// accumulates fp32 row sums via shfl-reduce + atomicAdd.
// Grid: x = compacted lower-tri block index (136), z = batch.
__global__ void __launch_bounds__(256) k_gemm_qk(
    const bf16_t* __restrict__ Q, const bf16_t* __restrict__ Kmat,
    bf16_t* __restrict__ P, float* __restrict__ rowsum) {
  const int lin = blockIdx.x;
  int by = (int)((sqrtf((float)(8 * lin + 1)) - 1.0f) * 0.5f);
  while ((by + 1) * (by + 2) / 2 <= lin) ++by;
  while (by * (by + 1) / 2 > lin) --by;
  const int bx = lin - by * (by + 1) / 2;
  const int b = blockIdx.z;

  __shared__ bf16_t ldsA[BM * BK];
  __shared__ bf16_t ldsB[BN * BK];
  floatx4 acc[4][4];
  const bf16_t* Ab = Q + (size_t)b * 2048 * 1024;
  const bf16_t* Bb = Kmat + (size_t)b * 2048 * 1024;
  const int rowBase = by * BM, colBase = bx * BN;
  gemm_bt_core(Ab, 1024, Bb, 1024, rowBase, colBase, 1024 / BK, ldsA, ldsB, acc);

  bf16_t* Pb = P + (size_t)b * 2048 * 2048;
  float* rs = rowsum + (size_t)b * 2048;
  EPILOGUE_SETUP();
  const bool offdiag = (bx < by);

  float partial[4][4];   // [i][rr] row-sum partial over this lane's 4 j cols
#pragma unroll
  for (int i = 0; i < 4; ++i)
#pragma unroll
    for (int rr = 0; rr < 4; ++rr) partial[i][rr] = 0.f;

#pragma unroll
  for (int i = 0; i < 4; ++i) {
    const int m0 = rowBase + wy * 64 + i * 16 + quad * 4;
#pragma unroll
    for (int j = 0; j < 4; ++j) {
      const int n = colBase + wx * 64 + j * 16 + r16;
#pragma unroll
      for (int rr = 0; rr < 4; ++rr) {
        const int m = m0 + rr;
        const float e = (offdiag || n <= m) ? __expf(acc[i][j][rr]) : 0.0f;
        Pb[(size_t)m * 2048 + n] = (bf16_t)e;
        partial[i][rr] += e;
      }
    }
  }
  // reduce over the 16 lanes of each quad group (xor masks 1,2,4,8 stay in-group)
#pragma unroll
  for (int i = 0; i < 4; ++i)
#pragma unroll
    for (int rr = 0; rr < 4; ++rr) {
      float v = partial[i][rr];
      v += __shfl_xor(v, 1, 64);
      v += __shfl_xor(v, 2, 64);
      v += __shfl_xor(v, 4, 64);
      v += __shfl_xor(v, 8, 64);
      partial[i][rr] = v;
    }
  if (r16 == 0) {
#pragma unroll
    for (int i = 0; i < 4; ++i) {
      const int m0 = rowBase + wy * 64 + i * 16 + quad * 4;
#pragma unroll
      for (int rr = 0; rr < 4; ++rr)
        atomicAdd(&rs[m0 + rr], partial[i][rr]);
    }
  }
}

// PV: O[b][2048][1024] = (P_unnorm @ Vt^T) * (1/rowsum). Causal K-bound,
// heavy-blocks-first remap.
__global__ void __launch_bounds__(256) k_gemm_pv(
    const bf16_t* __restrict__ P, const bf16_t* __restrict__ Vt,
    const float* __restrict__ rowsum, bf16_t* __restrict__ O) {
  const int bx = blockIdx.x, by = 15 - blockIdx.y, b = blockIdx.z;
  __shared__ bf16_t ldsA[BM * BK];
  __shared__ bf16_t ldsB[BN * BK];
  floatx4 acc[4][4];
  const bf16_t* Ab = P + (size_t)b * 2048 * 2048;
  const bf16_t* Bb = Vt + (size_t)b * 1024 * 2048;
  const int rowBase = by * BM, colBase = bx * BN;
  gemm_bt_core(Ab, 2048, Bb, 2048, rowBase, colBase, (by + 1) * 4, ldsA, ldsB, acc);
  bf16_t* C = O + (size_t)b * 2048 * 1024;
  const float* rs = rowsum + (size_t)b * 2048;
  EPILOGUE_SETUP();
#pragma unroll
  for (int i = 0; i < 4; ++i) {
    const int m0 = rowBase + wy * 64 + i * 16 + quad * 4;
#pragma unroll
    for (int rr = 0; rr < 4; ++rr) {
      const float inv = 1.0f / rs[m0 + rr];
#pragma unroll
      for (int j = 0; j < 4; ++j) {
        const int n = colBase + wx * 64 + j * 16 + r16;
        C[(size_t)(m0 + rr) * 1024 + n] = (bf16_t)(acc[i][j][rr] * inv);
      }
    }
  }
}

// out-proj: out[8192,1024] fp32 = O @ Wout_t^T + bias
__global__ void __launch_bounds__(256) k_gemm_out(
    const bf16_t* __restrict__ O, const bf16_t* __restrict__ Wt,
    const float* __restrict__ bias, float* __restrict__ out) {
  __shared__ bf16_t ldsA[BM * BK];
  __shared__ bf16_t ldsB[BN * BK];
  floatx4 acc[4][4];
  const int rowBase = blockIdx.y * BM;
  const int colBase = blockIdx.x * BN;
  gemm_bt_core(O, 1024, Wt, 1024, rowBase, colBase, 1024 / BK, ldsA, ldsB, acc);
  EPILOGUE_SETUP();
#pragma unroll
  for (int i = 0; i < 4; ++i) {
    const int m0 = rowBase + wy * 64 + i * 16 + quad * 4;
#pragma unroll
    for (int j = 0; j < 4; ++j) {
      const int n = colBase + wx * 64 + j * 16 + r16;
      const float bb = bias[n];
#pragma unroll
      for (int rr = 0; rr < 4; ++rr)
        out[(size_t)(m0 + rr) * 1024 + n] = acc[i][j][rr] + bb;
    }
  }
}

// ---------------- launch ----------------
// ws layout (bytes):
//   xb     @ 0          16,777,216   x as bf16 [8192,1024]
//   wqkvt  @ 16777216    6,291,456   w_qkv^T bf16 [3072,1024]
//   woutt  @ 23068672    2,097,152   w_out^T bf16 [1024,1024]
//   q      @ 25165824   16,777,216   [b,s,1024] bf16 (pre-scaled by 2^-5)
//   k      @ 41943040   16,777,216   [b,s,1024] bf16
//   vt     @ 58720256   16,777,216   [b,1024,s] bf16 (V transposed)
//   rowsum @ 75497472       32,768   [b,s] fp32 sum of exp
//   p      @ 142606336  33,554,432   [b,s,s] bf16 unnormalized exp(logit)
//   o      @ 176160768  16,777,216   [b,s,1024] bf16
extern "C" void kernel_launch(void* const* d_in, const int* in_sizes, int n_in,
                              void* d_out, int out_size, void* d_ws, size_t ws_size,
                              hipStream_t stream) {
  const float* x     = (const float*)d_in[0];
  const float* w_qkv = (const float*)d_in[1];
  const float* w_out = (const float*)d_in[2];
  const float* b_out = (const float*)d_in[3];
  float* out = (float*)d_out;
  char* ws = (char*)d_ws;

  bf16_t* xb     = (bf16_t*)(ws + 0);
  bf16_t* wqt    = (bf16_t*)(ws + 16777216);
  bf16_t* wot    = (bf16_t*)(ws + 23068672);
  bf16_t* q      = (bf16_t*)(ws + 25165824);
  bf16_t* kmat   = (bf16_t*)(ws + 41943040);
  bf16_t* vt     = (bf16_t*)(ws + 58720256);
  float*  rowsum = (float*)(ws + 75497472);
  bf16_t* p      = (bf16_t*)(ws + 142606336);
  bf16_t* o      = (bf16_t*)(ws + 176160768);

  k_cvt_bf16<<<8192, 256, 0, stream>>>(x, xb, rowsum);
  k_transpose_cvt<<<dim3(128, 32), dim3(32, 8), 0, stream>>>(w_qkv, wqt, w_out, wot);
  k_gemm_qkv<<<dim3(24, 64), 256, 0, stream>>>(xb, wqt, q, kmat, vt);
  k_gemm_qk<<<dim3(136, 1, 4), 256, 0, stream>>>(q, kmat, p, rowsum);
  k_gemm_pv<<<dim3(8, 16, 4), 256, 0, stream>>>(p, vt, rowsum, o);
  k_gemm_out<<<dim3(8, 64), 256, 0, stream>>>(o, wot, b_out, out);
}

// Round 4
// 277.107 us; speedup vs baseline: 1.2098x; 1.0341x over previous
//
#include <hip/hip_runtime.h>

typedef __bf16 bf16_t;
typedef __bf16 bf16x8 __attribute__((ext_vector_type(8)));
typedef __bf16 bf16x4 __attribute__((ext_vector_type(4)));
typedef float  floatx4 __attribute__((ext_vector_type(4)));

#define BM 128
#define BN 128
#define BK 32

// async global->LDS, 16B per lane. LDS dest must be wave-uniform base + lane*16.
__device__ __forceinline__ void gld_lds16(const bf16_t* g, bf16_t* l) {
  __builtin_amdgcn_global_load_lds(
      (__attribute__((address_space(1))) const void*)g,
      (__attribute__((address_space(3))) void*)l, 16, 0, 0);
}

// C[128x128] = A[M,K] @ Bt[N,K]^T tile. 256 threads = 4 waves in 2x2.
__device__ __forceinline__ void gemm_bt_core(
    const bf16_t* __restrict__ A, int lda,
    const bf16_t* __restrict__ Bt, int ldb,
    int rowBase, int colBase, int kTiles,
    bf16_t* ldsA, bf16_t* ldsB, floatx4 acc[4][4])
{
  const int t    = threadIdx.x;
  const int lane = t & 63;
  const int wave = t >> 6;
  const int wy   = wave >> 1;
  const int wx   = wave & 1;
  const int quad = lane >> 4;
  const int r16  = lane & 15;

  const bf16_t* ga = A  + (size_t)(rowBase + (t >> 2)) * lda + (t & 3) * 8;
  const bf16_t* gb = Bt + (size_t)(colBase + (t >> 2)) * ldb + (t & 3) * 8;
  bf16_t* la = ldsA + t * 8;
  bf16_t* lb = ldsB + t * 8;

#pragma unroll
  for (int i = 0; i < 4; ++i)
#pragma unroll
    for (int j = 0; j < 4; ++j)
      acc[i][j] = (floatx4){0.f, 0.f, 0.f, 0.f};

  for (int kt = 0; kt < kTiles; ++kt) {
    const int k0 = kt * BK;
    gld_lds16(ga + k0,                    la);
    gld_lds16(ga + k0 + (size_t)64 * lda, la + 64 * BK);
    gld_lds16(gb + k0,                    lb);
    gld_lds16(gb + k0 + (size_t)64 * ldb, lb + 64 * BK);
    __syncthreads();

    bf16x8 af[4], bfr[4];
#pragma unroll
    for (int i = 0; i < 4; ++i)
      af[i] = *(const bf16x8*)(ldsA + (wy * 64 + i * 16 + r16) * BK + quad * 8);
#pragma unroll
    for (int j = 0; j < 4; ++j)
      bfr[j] = *(const bf16x8*)(ldsB + (wx * 64 + j * 16 + r16) * BK + quad * 8);
#pragma unroll
    for (int i = 0; i < 4; ++i)
#pragma unroll
      for (int j = 0; j < 4; ++j)
        acc[i][j] = __builtin_amdgcn_mfma_f32_16x16x32_bf16(af[i], bfr[j], acc[i][j], 0, 0, 0);
    __syncthreads();
  }
}

#define EPILOGUE_SETUP()                       \
  const int t    = threadIdx.x;                \
  const int lane = t & 63;                     \
  const int wave = t >> 6;                     \
  const int wy   = wave >> 1;                  \
  const int wx   = wave & 1;                   \
  const int quad = lane >> 4;                  \
  const int r16  = lane & 15;

// ---------------- fused prep kernel ----------------
// blocks [0,4096): x fp32 -> bf16, 8 elems/thread; blocks [0,32) also zero rowsum
// blocks [4096,7168): transpose+cvt w_qkv [1024,3072] -> [3072,1024]
// blocks [7168,8192): transpose+cvt w_out [1024,1024] -> [1024,1024]
__global__ void __launch_bounds__(256) k_prep(
    const float* __restrict__ x, bf16_t* __restrict__ xb,
    const float* __restrict__ w_qkv, bf16_t* __restrict__ wqt,
    const float* __restrict__ w_out, bf16_t* __restrict__ wot,
    float* __restrict__ rowsum) {
  __shared__ float tile[32][33];
  const int bxk = blockIdx.x;
  const int t = threadIdx.x;
  if (bxk < 4096) {
    const size_t idx = (size_t)bxk * 256 + t;
    if (bxk < 32) rowsum[idx] = 0.0f;
    const float4 v0 = ((const float4*)x)[idx * 2];
    const float4 v1 = ((const float4*)x)[idx * 2 + 1];
    bf16x8 o;
    o[0] = (bf16_t)v0.x; o[1] = (bf16_t)v0.y; o[2] = (bf16_t)v0.z; o[3] = (bf16_t)v0.w;
    o[4] = (bf16_t)v1.x; o[5] = (bf16_t)v1.y; o[6] = (bf16_t)v1.z; o[7] = (bf16_t)v1.w;
    ((bf16x8*)xb)[idx] = o;
    return;
  }
  const bool first = bxk < 7168;
  const int tb = first ? (bxk - 4096) : (bxk - 7168);
  const float* in = first ? w_qkv : w_out;
  bf16_t* out = first ? wqt : wot;
  const int C = first ? 3072 : 1024;
  const int nCB = C >> 5;
  const int c0 = (tb % nCB) * 32;
  const int r0 = (tb / nCB) * 32;
  const int tx = t & 31, ty = t >> 5;
#pragma unroll
  for (int rr = 0; rr < 32; rr += 8)
    tile[ty + rr][tx] = in[(size_t)(r0 + ty + rr) * C + (c0 + tx)];
  __syncthreads();
#pragma unroll
  for (int cc = 0; cc < 32; cc += 8)
    out[(size_t)(c0 + ty + cc) * 1024 + (r0 + tx)] = (bf16_t)tile[tx][ty + cc];
}

// ---------------- GEMM kernels ----------------

// QKV: C[8192,3072] = Xb @ Wqkv_t^T ; scatter q (pre-scaled 2^-5) / k / v_t.
// Grid swizzled into 8-row super-bands for L2 locality on B.
__global__ void __launch_bounds__(256) k_gemm_qkv(
    const bf16_t* __restrict__ X, const bf16_t* __restrict__ Wt,
    bf16_t* __restrict__ Q, bf16_t* __restrict__ Kmat, bf16_t* __restrict__ Vt) {
  __shared__ bf16_t ldsA[BM * BK];
  __shared__ bf16_t ldsB[BN * BK];
  floatx4 acc[4][4];
  const int lin = blockIdx.y * 24 + blockIdx.x;
  const int st = lin / 192, r = lin % 192;
  const int by = st * 8 + (r & 7);
  const int bx = r >> 3;
  const int rowBase = by * BM;
  const int colBase = bx * BN;
  gemm_bt_core(X, 1024, Wt, 1024, rowBase, colBase, 1024 / BK, ldsA, ldsB, acc);
  EPILOGUE_SETUP();
  if (colBase < 1024) {
#pragma unroll
    for (int i = 0; i < 4; ++i) {
      const int m0 = rowBase + wy * 64 + i * 16 + quad * 4;
#pragma unroll
      for (int j = 0; j < 4; ++j) {
        const int n = colBase + wx * 64 + j * 16 + r16;
#pragma unroll
        for (int rr = 0; rr < 4; ++rr)
          Q[(size_t)(m0 + rr) * 1024 + n] = (bf16_t)(acc[i][j][rr] * 0.03125f);
      }
    }
  } else if (colBase < 2048) {
    const int nb = colBase - 1024;
#pragma unroll
    for (int i = 0; i < 4; ++i) {
      const int m0 = rowBase + wy * 64 + i * 16 + quad * 4;
#pragma unroll
      for (int j = 0; j < 4; ++j) {
        const int n = nb + wx * 64 + j * 16 + r16;
#pragma unroll
        for (int rr = 0; rr < 4; ++rr)
          Kmat[(size_t)(m0 + rr) * 1024 + n] = (bf16_t)acc[i][j][rr];
      }
    }
  } else {
    const int nb = colBase - 2048;
    const int b = rowBase >> 11;
#pragma unroll
    for (int i = 0; i < 4; ++i) {
      const int m0 = rowBase + wy * 64 + i * 16 + quad * 4;
      const int s0 = m0 & 2047;
#pragma unroll
      for (int j = 0; j < 4; ++j) {
        const int n = nb + wx * 64 + j * 16 + r16;
        bf16x4 pk;
#pragma unroll
        for (int rr = 0; rr < 4; ++rr) pk[rr] = (bf16_t)acc[i][j][rr];
        *(bf16x4*)(Vt + (size_t)(b * 1024 + n) * 2048 + s0) = pk;
      }
    }
  }
}

// QK^T + exp fused. Q pre-scaled so acc == logit (|logit| << 88, no max-sub).
// Writes p_unnorm bf16 (masked -> 0); fp32 row sums via quad-shfl + atomicAdd.
__global__ void __launch_bounds__(256) k_gemm_qk(
    const bf16_t* __restrict__ Q, const bf16_t* __restrict__ Kmat,
    bf16_t* __restrict__ P, float* __restrict__ rowsum) {
  const int lin = blockIdx.x;
  int by = (int)((sqrtf((float)(8 * lin + 1)) - 1.0f) * 0.5f);
  while ((by + 1) * (by + 2) / 2 <= lin) ++by;
  while (by * (by + 1) / 2 > lin) --by;
  const int bx = lin - by * (by + 1) / 2;
  const int b = blockIdx.z;

  __shared__ bf16_t ldsA[BM * BK];
  __shared__ bf16_t ldsB[BN * BK];
  floatx4 acc[4][4];
  const bf16_t* Ab = Q + (size_t)b * 2048 * 1024;
  const bf16_t* Bb = Kmat + (size_t)b * 2048 * 1024;
  const int rowBase = by * BM, colBase = bx * BN;
  gemm_bt_core(Ab, 1024, Bb, 1024, rowBase, colBase, 1024 / BK, ldsA, ldsB, acc);

  bf16_t* Pb = P + (size_t)b * 2048 * 2048;
  float* rs = rowsum + (size_t)b * 2048;
  EPILOGUE_SETUP();
  const bool offdiag = (bx < by);

  float partial[4][4];
#pragma unroll
  for (int i = 0; i < 4; ++i)
#pragma unroll
    for (int rr = 0; rr < 4; ++rr) partial[i][rr] = 0.f;

#pragma unroll
  for (int i = 0; i < 4; ++i) {
    const int m0 = rowBase + wy * 64 + i * 16 + quad * 4;
#pragma unroll
    for (int j = 0; j < 4; ++j) {
      const int n = colBase + wx * 64 + j * 16 + r16;
#pragma unroll
      for (int rr = 0; rr < 4; ++rr) {
        const int m = m0 + rr;
        const float e = (offdiag || n <= m) ? __expf(acc[i][j][rr]) : 0.0f;
        Pb[(size_t)m * 2048 + n] = (bf16_t)e;
        partial[i][rr] += e;
      }
    }
  }
#pragma unroll
  for (int i = 0; i < 4; ++i)
#pragma unroll
    for (int rr = 0; rr < 4; ++rr) {
      float v = partial[i][rr];
      v += __shfl_xor(v, 1, 64);
      v += __shfl_xor(v, 2, 64);
      v += __shfl_xor(v, 4, 64);
      v += __shfl_xor(v, 8, 64);
      partial[i][rr] = v;
    }
  if (r16 == 0) {
#pragma unroll
    for (int i = 0; i < 4; ++i) {
      const int m0 = rowBase + wy * 64 + i * 16 + quad * 4;
#pragma unroll
      for (int rr = 0; rr < 4; ++rr)
        atomicAdd(&rs[m0 + rr], partial[i][rr]);
    }
  }
}

// PV: O = (P_unnorm @ Vt^T) * (1/rowsum). Causal K-bound.
// Linear grid 512; blocks l and l+256 (same CU under round-robin dispatch) get
// by = 15-u and by = u  ->  per-CU K-iter load is exactly 68 (balanced).
__global__ void __launch_bounds__(256) k_gemm_pv(
    const bf16_t* __restrict__ P, const bf16_t* __restrict__ Vt,
    const float* __restrict__ rowsum, bf16_t* __restrict__ O) {
  const int l = blockIdx.x;
  const int z = l >> 8;
  const int idx = l & 255;
  const int bx = idx & 7;
  const int u = (idx >> 3) & 7;
  const int b = idx >> 6;
  const int by = z ? u : (15 - u);

  __shared__ bf16_t ldsA[BM * BK];
  __shared__ bf16_t ldsB[BN * BK];
  floatx4 acc[4][4];
  const bf16_t* Ab = P + (size_t)b * 2048 * 2048;
  const bf16_t* Bb = Vt + (size_t)b * 1024 * 2048;
  const int rowBase = by * BM, colBase = bx * BN;
  gemm_bt_core(Ab, 2048, Bb, 2048, rowBase, colBase, (by + 1) * 4, ldsA, ldsB, acc);
  bf16_t* C = O + (size_t)b * 2048 * 1024;
  const float* rs = rowsum + (size_t)b * 2048;
  EPILOGUE_SETUP();
#pragma unroll
  for (int i = 0; i < 4; ++i) {
    const int m0 = rowBase + wy * 64 + i * 16 + quad * 4;
#pragma unroll
    for (int rr = 0; rr < 4; ++rr) {
      const float inv = 1.0f / rs[m0 + rr];
#pragma unroll
      for (int j = 0; j < 4; ++j) {
        const int n = colBase + wx * 64 + j * 16 + r16;
        C[(size_t)(m0 + rr) * 1024 + n] = (bf16_t)(acc[i][j][rr] * inv);
      }
    }
  }
}

// out-proj: out[8192,1024] fp32 = O @ Wout_t^T + bias
__global__ void __launch_bounds__(256) k_gemm_out(
    const bf16_t* __restrict__ O, const bf16_t* __restrict__ Wt,
    const float* __restrict__ bias, float* __restrict__ out) {
  __shared__ bf16_t ldsA[BM * BK];
  __shared__ bf16_t ldsB[BN * BK];
  floatx4 acc[4][4];
  const int rowBase = blockIdx.y * BM;
  const int colBase = blockIdx.x * BN;
  gemm_bt_core(O, 1024, Wt, 1024, rowBase, colBase, 1024 / BK, ldsA, ldsB, acc);
  EPILOGUE_SETUP();
#pragma unroll
  for (int i = 0; i < 4; ++i) {
    const int m0 = rowBase + wy * 64 + i * 16 + quad * 4;
#pragma unroll
    for (int j = 0; j < 4; ++j) {
      const int n = colBase + wx * 64 + j * 16 + r16;
      const float bb = bias[n];
#pragma unroll
      for (int rr = 0; rr < 4; ++rr)
        out[(size_t)(m0 + rr) * 1024 + n] = acc[i][j][rr] + bb;
    }
  }
}

// ---------------- launch ----------------
// ws layout (bytes):
//   xb     @ 0          16,777,216   x as bf16 [8192,1024]
//   wqkvt  @ 16777216    6,291,456   w_qkv^T bf16 [3072,1024]
//   woutt  @ 23068672    2,097,152   w_out^T bf16 [1024,1024]
//   q      @ 25165824   16,777,216   [b,s,1024] bf16 (pre-scaled by 2^-5)
//   k      @ 41943040   16,777,216   [b,s,1024] bf16
//   vt     @ 58720256   16,777,216   [b,1024,s] bf16 (V transposed)
//   rowsum @ 75497472       32,768   [b,s] fp32 sum of exp
//   p      @ 142606336  33,554,432   [b,s,s] bf16 unnormalized exp(logit)
//   o      @ 176160768  16,777,216   [b,s,1024] bf16
extern "C" void kernel_launch(void* const* d_in, const int* in_sizes, int n_in,
                              void* d_out, int out_size, void* d_ws, size_t ws_size,
                              hipStream_t stream) {
  const float* x     = (const float*)d_in[0];
  const float* w_qkv = (const float*)d_in[1];
  const float* w_out = (const float*)d_in[2];
  const float* b_out = (const float*)d_in[3];
  float* out = (float*)d_out;
  char* ws = (char*)d_ws;

  bf16_t* xb     = (bf16_t*)(ws + 0);
  bf16_t* wqt    = (bf16_t*)(ws + 16777216);
  bf16_t* wot    = (bf16_t*)(ws + 23068672);
  bf16_t* q      = (bf16_t*)(ws + 25165824);
  bf16_t* kmat   = (bf16_t*)(ws + 41943040);
  bf16_t* vt     = (bf16_t*)(ws + 58720256);
  float*  rowsum = (float*)(ws + 75497472);
  bf16_t* p      = (bf16_t*)(ws + 142606336);
  bf16_t* o      = (bf16_t*)(ws + 176160768);

  k_prep<<<8192, 256, 0, stream>>>(x, xb, w_qkv, wqt, w_out, wot, rowsum);
  k_gemm_qkv<<<dim3(24, 64), 256, 0, stream>>>(xb, wqt, q, kmat, vt);
  k_gemm_qk<<<dim3(136, 1, 4), 256, 0, stream>>>(q, kmat, p, rowsum);
  k_gemm_pv<<<512, 256, 0, stream>>>(p, vt, rowsum, o);
  k_gemm_out<<<dim3(8, 64), 256, 0, stream>>>(o, wot, b_out, out);
}

// Round 5
// 269.052 us; speedup vs baseline: 1.2460x; 1.0299x over previous
//
#include <hip/hip_runtime.h>

typedef __bf16 bf16_t;
typedef __bf16 bf16x8 __attribute__((ext_vector_type(8)));
typedef __bf16 bf16x4 __attribute__((ext_vector_type(4)));
typedef float  floatx4 __attribute__((ext_vector_type(4)));

#define BM 128
#define BN 128
#define BK 64

// async global->LDS, 16B per lane. LDS dest is wave-uniform base + lane*16 (no
// scatter, no padding) — so conflict-avoidance is done by permuting the GLOBAL
// chunk each lane fetches (XOR swizzle), not the LDS address.
__device__ __forceinline__ void gld_lds16(const bf16_t* g, bf16_t* l) {
  __builtin_amdgcn_global_load_lds(
      (__attribute__((address_space(1))) const void*)g,
      (__attribute__((address_space(3))) void*)l, 16, 0, 0);
}

// C[128x128] = A[M,K] @ Bt[N,K]^T tile. 256 threads = 4 waves in 2x2, each wave
// 64x64 via 4x4 mfma_f32_16x16x32_bf16. BK=64: 32 MFMA per barrier pair.
// LDS layout: row-major 128x64, but chunk s of row r holds global chunk s^(r&7)
// -> ds_read_b128 of a fragment is conflict-free (2-way max).
__device__ __forceinline__ void gemm_bt_core(
    const bf16_t* __restrict__ A, int lda,
    const bf16_t* __restrict__ Bt, int ldb,
    int rowBase, int colBase, int kTiles,   // kTiles counts BK=64 tiles
    bf16_t* ldsA, bf16_t* ldsB, floatx4 acc[4][4])
{
  const int t    = threadIdx.x;
  const int lane = t & 63;
  const int wave = t >> 6;
  const int wy   = wave >> 1;
  const int wx   = wave & 1;
  const int quad = lane >> 4;
  const int r16  = lane & 15;

  // staging: one issue = 256 lanes x 16B = 4KB = 32 rows of 128B
  const int srow   = t >> 3;                  // 0..31
  const int schunk = (t & 7) ^ (srow & 7);    // swizzled global chunk
  const bf16_t* ga = A  + (size_t)(rowBase + srow) * lda + schunk * 8;
  const bf16_t* gb = Bt + (size_t)(colBase + srow) * ldb + schunk * 8;
  bf16_t* la = ldsA + t * 8;                  // linear LDS, 16B per lane
  bf16_t* lb = ldsB + t * 8;

#pragma unroll
  for (int i = 0; i < 4; ++i)
#pragma unroll
    for (int j = 0; j < 4; ++j)
      acc[i][j] = (floatx4){0.f, 0.f, 0.f, 0.f};

  for (int kt = 0; kt < kTiles; ++kt) {
    const int k0 = kt * BK;
#pragma unroll
    for (int is = 0; is < 4; ++is) {          // 4 issues x 32 rows = 128 rows
      gld_lds16(ga + k0 + (size_t)(32 * is) * lda, la + is * (32 * BK));
      gld_lds16(gb + k0 + (size_t)(32 * is) * ldb, lb + is * (32 * BK));
    }
    __syncthreads();

#pragma unroll
    for (int h = 0; h < 2; ++h) {             // two K=32 halves per staged tile
      bf16x8 af[4], bfr[4];
#pragma unroll
      for (int i = 0; i < 4; ++i) {
        const int r = wy * 64 + i * 16 + r16;
        af[i] = *(const bf16x8*)(ldsA + r * BK + (((h << 2) + quad) ^ (r16 & 7)) * 8);
      }
#pragma unroll
      for (int j = 0; j < 4; ++j) {
        const int r = wx * 64 + j * 16 + r16;
        bfr[j] = *(const bf16x8*)(ldsB + r * BK + (((h << 2) + quad) ^ (r16 & 7)) * 8);
      }
#pragma unroll
      for (int i = 0; i < 4; ++i)
#pragma unroll
        for (int j = 0; j < 4; ++j)
          acc[i][j] = __builtin_amdgcn_mfma_f32_16x16x32_bf16(af[i], bfr[j], acc[i][j], 0, 0, 0);
    }
    __syncthreads();
  }
}

#define EPILOGUE_SETUP()                       \
  const int t    = threadIdx.x;                \
  const int lane = t & 63;                     \
  const int wave = t >> 6;                     \
  const int wy   = wave >> 1;                  \
  const int wx   = wave & 1;                   \
  const int quad = lane >> 4;                  \
  const int r16  = lane & 15;

// ---------------- fused prep kernel ----------------
// blocks [0,4096): x fp32 -> bf16, 8 elems/thread; blocks [0,32) also zero rowsum
// blocks [4096,7168): transpose+cvt w_qkv [1024,3072] -> [3072,1024]
// blocks [7168,8192): transpose+cvt w_out [1024,1024] -> [1024,1024]
__global__ void __launch_bounds__(256) k_prep(
    const float* __restrict__ x, bf16_t* __restrict__ xb,
    const float* __restrict__ w_qkv, bf16_t* __restrict__ wqt,
    const float* __restrict__ w_out, bf16_t* __restrict__ wot,
    float* __restrict__ rowsum) {
  __shared__ float tile[32][33];
  const int bxk = blockIdx.x;
  const int t = threadIdx.x;
  if (bxk < 4096) {
    const size_t idx = (size_t)bxk * 256 + t;
    if (bxk < 32) rowsum[idx] = 0.0f;
    const float4 v0 = ((const float4*)x)[idx * 2];
    const float4 v1 = ((const float4*)x)[idx * 2 + 1];
    bf16x8 o;
    o[0] = (bf16_t)v0.x; o[1] = (bf16_t)v0.y; o[2] = (bf16_t)v0.z; o[3] = (bf16_t)v0.w;
    o[4] = (bf16_t)v1.x; o[5] = (bf16_t)v1.y; o[6] = (bf16_t)v1.z; o[7] = (bf16_t)v1.w;
    ((bf16x8*)xb)[idx] = o;
    return;
  }
  const bool first = bxk < 7168;
  const int tb = first ? (bxk - 4096) : (bxk - 7168);
  const float* in = first ? w_qkv : w_out;
  bf16_t* out = first ? wqt : wot;
  const int C = first ? 3072 : 1024;
  const int nCB = C >> 5;
  const int c0 = (tb % nCB) * 32;
  const int r0 = (tb / nCB) * 32;
  const int tx = t & 31, ty = t >> 5;
#pragma unroll
  for (int rr = 0; rr < 32; rr += 8)
    tile[ty + rr][tx] = in[(size_t)(r0 + ty + rr) * C + (c0 + tx)];
  __syncthreads();
#pragma unroll
  for (int cc = 0; cc < 32; cc += 8)
    out[(size_t)(c0 + ty + cc) * 1024 + (r0 + tx)] = (bf16_t)tile[tx][ty + cc];
}

// ---------------- GEMM kernels ----------------

// QKV: C[8192,3072] = Xb @ Wqkv_t^T ; scatter q (pre-scaled 2^-5) / k / v_t.
// Grid swizzled into 8-row super-bands for L2 locality on B.
__global__ void __launch_bounds__(256) k_gemm_qkv(
    const bf16_t* __restrict__ X, const bf16_t* __restrict__ Wt,
    bf16_t* __restrict__ Q, bf16_t* __restrict__ Kmat, bf16_t* __restrict__ Vt) {
  __shared__ bf16_t ldsA[BM * BK];
  __shared__ bf16_t ldsB[BN * BK];
  floatx4 acc[4][4];
  const int lin = blockIdx.y * 24 + blockIdx.x;
  const int st = lin / 192, r = lin % 192;
  const int by = st * 8 + (r & 7);
  const int bx = r >> 3;
  const int rowBase = by * BM;
  const int colBase = bx * BN;
  gemm_bt_core(X, 1024, Wt, 1024, rowBase, colBase, 1024 / BK, ldsA, ldsB, acc);
  EPILOGUE_SETUP();
  if (colBase < 1024) {
#pragma unroll
    for (int i = 0; i < 4; ++i) {
      const int m0 = rowBase + wy * 64 + i * 16 + quad * 4;
#pragma unroll
      for (int j = 0; j < 4; ++j) {
        const int n = colBase + wx * 64 + j * 16 + r16;
#pragma unroll
        for (int rr = 0; rr < 4; ++rr)
          Q[(size_t)(m0 + rr) * 1024 + n] = (bf16_t)(acc[i][j][rr] * 0.03125f);
      }
    }
  } else if (colBase < 2048) {
    const int nb = colBase - 1024;
#pragma unroll
    for (int i = 0; i < 4; ++i) {
      const int m0 = rowBase + wy * 64 + i * 16 + quad * 4;
#pragma unroll
      for (int j = 0; j < 4; ++j) {
        const int n = nb + wx * 64 + j * 16 + r16;
#pragma unroll
        for (int rr = 0; rr < 4; ++rr)
          Kmat[(size_t)(m0 + rr) * 1024 + n] = (bf16_t)acc[i][j][rr];
      }
    }
  } else {
    const int nb = colBase - 2048;
    const int b = rowBase >> 11;
#pragma unroll
    for (int i = 0; i < 4; ++i) {
      const int m0 = rowBase + wy * 64 + i * 16 + quad * 4;
      const int s0 = m0 & 2047;
#pragma unroll
      for (int j = 0; j < 4; ++j) {
        const int n = nb + wx * 64 + j * 16 + r16;
        bf16x4 pk;
#pragma unroll
        for (int rr = 0; rr < 4; ++rr) pk[rr] = (bf16_t)acc[i][j][rr];
        *(bf16x4*)(Vt + (size_t)(b * 1024 + n) * 2048 + s0) = pk;
      }
    }
  }
}

// QK^T + exp fused. Q pre-scaled so acc == logit (|logit| << 88, no max-sub).
// Writes p_unnorm bf16 (masked -> 0); fp32 row sums via quad-shfl + atomicAdd.
__global__ void __launch_bounds__(256) k_gemm_qk(
    const bf16_t* __restrict__ Q, const bf16_t* __restrict__ Kmat,
    bf16_t* __restrict__ P, float* __restrict__ rowsum) {
  const int lin = blockIdx.x;
  int by = (int)((sqrtf((float)(8 * lin + 1)) - 1.0f) * 0.5f);
  while ((by + 1) * (by + 2) / 2 <= lin) ++by;
  while (by * (by + 1) / 2 > lin) --by;
  const int bx = lin - by * (by + 1) / 2;
  const int b = blockIdx.z;

  __shared__ bf16_t ldsA[BM * BK];
  __shared__ bf16_t ldsB[BN * BK];
  floatx4 acc[4][4];
  const bf16_t* Ab = Q + (size_t)b * 2048 * 1024;
  const bf16_t* Bb = Kmat + (size_t)b * 2048 * 1024;
  const int rowBase = by * BM, colBase = bx * BN;
  gemm_bt_core(Ab, 1024, Bb, 1024, rowBase, colBase, 1024 / BK, ldsA, ldsB, acc);

  bf16_t* Pb = P + (size_t)b * 2048 * 2048;
  float* rs = rowsum + (size_t)b * 2048;
  EPILOGUE_SETUP();
  const bool offdiag = (bx < by);

  float partial[4][4];
#pragma unroll
  for (int i = 0; i < 4; ++i)
#pragma unroll
    for (int rr = 0; rr < 4; ++rr) partial[i][rr] = 0.f;

#pragma unroll
  for (int i = 0; i < 4; ++i) {
    const int m0 = rowBase + wy * 64 + i * 16 + quad * 4;
#pragma unroll
    for (int j = 0; j < 4; ++j) {
      const int n = colBase + wx * 64 + j * 16 + r16;
#pragma unroll
      for (int rr = 0; rr < 4; ++rr) {
        const int m = m0 + rr;
        const float e = (offdiag || n <= m) ? __expf(acc[i][j][rr]) : 0.0f;
        Pb[(size_t)m * 2048 + n] = (bf16_t)e;
        partial[i][rr] += e;
      }
    }
  }
#pragma unroll
  for (int i = 0; i < 4; ++i)
#pragma unroll
    for (int rr = 0; rr < 4; ++rr) {
      float v = partial[i][rr];
      v += __shfl_xor(v, 1, 64);
      v += __shfl_xor(v, 2, 64);
      v += __shfl_xor(v, 4, 64);
      v += __shfl_xor(v, 8, 64);
      partial[i][rr] = v;
    }
  if (r16 == 0) {
#pragma unroll
    for (int i = 0; i < 4; ++i) {
      const int m0 = rowBase + wy * 64 + i * 16 + quad * 4;
#pragma unroll
      for (int rr = 0; rr < 4; ++rr)
        atomicAdd(&rs[m0 + rr], partial[i][rr]);
    }
  }
}

// PV: O = (P_unnorm @ Vt^T) * (1/rowsum). Causal K-bound.
// Linear grid 512; blocks l and l+256 (same CU under round-robin dispatch) get
// by = 15-u and by = u  ->  per-CU K-iter load balanced.
__global__ void __launch_bounds__(256) k_gemm_pv(
    const bf16_t* __restrict__ P, const bf16_t* __restrict__ Vt,
    const float* __restrict__ rowsum, bf16_t* __restrict__ O) {
  const int l = blockIdx.x;
  const int z = l >> 8;
  const int idx = l & 255;
  const int bx = idx & 7;
  const int u = (idx >> 3) & 7;
  const int b = idx >> 6;
  const int by = z ? u : (15 - u);

  __shared__ bf16_t ldsA[BM * BK];
  __shared__ bf16_t ldsB[BN * BK];
  floatx4 acc[4][4];
  const bf16_t* Ab = P + (size_t)b * 2048 * 2048;
  const bf16_t* Bb = Vt + (size_t)b * 1024 * 2048;
  const int rowBase = by * BM, colBase = bx * BN;
  gemm_bt_core(Ab, 2048, Bb, 2048, rowBase, colBase, (by + 1) * 2, ldsA, ldsB, acc);
  bf16_t* C = O + (size_t)b * 2048 * 1024;
  const float* rs = rowsum + (size_t)b * 2048;
  EPILOGUE_SETUP();
#pragma unroll
  for (int i = 0; i < 4; ++i) {
    const int m0 = rowBase + wy * 64 + i * 16 + quad * 4;
#pragma unroll
    for (int rr = 0; rr < 4; ++rr) {
      const float inv = 1.0f / rs[m0 + rr];
#pragma unroll
      for (int j = 0; j < 4; ++j) {
        const int n = colBase + wx * 64 + j * 16 + r16;
        C[(size_t)(m0 + rr) * 1024 + n] = (bf16_t)(acc[i][j][rr] * inv);
      }
    }
  }
}

// out-proj: out[8192,1024] fp32 = O @ Wout_t^T + bias
__global__ void __launch_bounds__(256) k_gemm_out(
    const bf16_t* __restrict__ O, const bf16_t* __restrict__ Wt,
    const float* __restrict__ bias, float* __restrict__ out) {
  __shared__ bf16_t ldsA[BM * BK];
  __shared__ bf16_t ldsB[BN * BK];
  floatx4 acc[4][4];
  const int rowBase = blockIdx.y * BM;
  const int colBase = blockIdx.x * BN;
  gemm_bt_core(O, 1024, Wt, 1024, rowBase, colBase, 1024 / BK, ldsA, ldsB, acc);
  EPILOGUE_SETUP();
#pragma unroll
  for (int i = 0; i < 4; ++i) {
    const int m0 = rowBase + wy * 64 + i * 16 + quad * 4;
#pragma unroll
    for (int j = 0; j < 4; ++j) {
      const int n = colBase + wx * 64 + j * 16 + r16;
      const float bb = bias[n];
#pragma unroll
      for (int rr = 0; rr < 4; ++rr)
        out[(size_t)(m0 + rr) * 1024 + n] = acc[i][j][rr] + bb;
    }
  }
}

// ---------------- launch ----------------
// ws layout (bytes):
//   xb     @ 0          16,777,216   x as bf16 [8192,1024]
//   wqkvt  @ 16777216    6,291,456   w_qkv^T bf16 [3072,1024]
//   woutt  @ 23068672    2,097,152   w_out^T bf16 [1024,1024]
//   q      @ 25165824   16,777,216   [b,s,1024] bf16 (pre-scaled by 2^-5)
//   k      @ 41943040   16,777,216   [b,s,1024] bf16
//   vt     @ 58720256   16,777,216   [b,1024,s] bf16 (V transposed)
//   rowsum @ 75497472       32,768   [b,s] fp32 sum of exp
//   p      @ 142606336  33,554,432   [b,s,s] bf16 unnormalized exp(logit)
//   o      @ 176160768  16,777,216   [b,s,1024] bf16
extern "C" void kernel_launch(void* const* d_in, const int* in_sizes, int n_in,
                              void* d_out, int out_size, void* d_ws, size_t ws_size,
                              hipStream_t stream) {
  const float* x     = (const float*)d_in[0];
  const float* w_qkv = (const float*)d_in[1];
  const float* w_out = (const float*)d_in[2];
  const float* b_out = (const float*)d_in[3];
  float* out = (float*)d_out;
  char* ws = (char*)d_ws;

  bf16_t* xb     = (bf16_t*)(ws + 0);
  bf16_t* wqt    = (bf16_t*)(ws + 16777216);
  bf16_t* wot    = (bf16_t*)(ws + 23068672);
  bf16_t* q      = (bf16_t*)(ws + 25165824);
  bf16_t* kmat   = (bf16_t*)(ws + 41943040);
  bf16_t* vt     = (bf16_t*)(ws + 58720256);
  float*  rowsum = (float*)(ws + 75497472);
  bf16_t* p      = (bf16_t*)(ws + 142606336);
  bf16_t* o      = (bf16_t*)(ws + 176160768);

  k_prep<<<8192, 256, 0, stream>>>(x, xb, w_qkv, wqt, w_out, wot, rowsum);
  k_gemm_qkv<<<dim3(24, 64), 256, 0, stream>>>(xb, wqt, q, kmat, vt);
  k_gemm_qk<<<dim3(136, 1, 4), 256, 0, stream>>>(q, kmat, p, rowsum);
  k_gemm_pv<<<512, 256, 0, stream>>>(p, vt, rowsum, o);
  k_gemm_out<<<dim3(8, 64), 256, 0, stream>>>(o, wot, b_out, out);
}

// Round 6
// 267.673 us; speedup vs baseline: 1.2524x; 1.0052x over previous
//
#include <hip/hip_runtime.h>

typedef __bf16 bf16_t;
typedef __bf16 bf16x8 __attribute__((ext_vector_type(8)));
typedef __bf16 bf16x4 __attribute__((ext_vector_type(4)));
typedef float  floatx4 __attribute__((ext_vector_type(4)));

#define BM 128
#define BN 128
#define BK 64

// async global->LDS, 16B per lane. LDS dest is wave-uniform base + lane*16 (no
// scatter, no padding) — conflict-avoidance is done by permuting the GLOBAL
// chunk each lane fetches (XOR swizzle), not the LDS address.
__device__ __forceinline__ void gld_lds16(const bf16_t* g, bf16_t* l) {
  __builtin_amdgcn_global_load_lds(
      (__attribute__((address_space(1))) const void*)g,
      (__attribute__((address_space(3))) void*)l, 16, 0, 0);
}

// C[128x128] = A[M,K] @ Bt[N,K]^T tile. 256 threads = 4 waves in 2x2, each wave
// 64x64 via 4x4 mfma_f32_16x16x32_bf16. BK=64: 32 MFMA per barrier pair.
// LDS: row-major 128x64; chunk s of row r holds global chunk s^(r&7) -> frag
// ds_read_b128 is 2-way max (free). All frag/staging addresses hoisted.
__device__ __forceinline__ void gemm_bt_core(
    const bf16_t* __restrict__ A, int lda,
    const bf16_t* __restrict__ Bt, int ldb,
    int rowBase, int colBase, int kTiles,   // kTiles counts BK=64 tiles
    bf16_t* ldsA, bf16_t* ldsB, floatx4 acc[4][4])
{
  const int t    = threadIdx.x;
  const int lane = t & 63;
  const int wave = t >> 6;
  const int wy   = wave >> 1;
  const int wx   = wave & 1;
  const int quad = lane >> 4;
  const int r16  = lane & 15;

  // staging: one issue = 256 lanes x 16B = 4KB = 32 rows of 128B
  const int srow   = t >> 3;                  // 0..31
  const int schunk = (t & 7) ^ (srow & 7);    // swizzled global chunk
  // hoisted running global pointers (+= BK per iter)
  const bf16_t* gA[4];
  const bf16_t* gB[4];
#pragma unroll
  for (int is = 0; is < 4; ++is) {
    gA[is] = A  + (size_t)(rowBase + 32 * is + srow) * lda + schunk * 8;
    gB[is] = Bt + (size_t)(colBase + 32 * is + srow) * ldb + schunk * 8;
  }
  bf16_t* la = ldsA + t * 8;                  // linear LDS, 16B per lane
  bf16_t* lb = ldsB + t * 8;

  // hoisted LDS fragment pointers (kt-invariant)
  const bf16_t* pA[2][4];
  const bf16_t* pB[2][4];
#pragma unroll
  for (int h = 0; h < 2; ++h) {
    const int chunk = (((h << 2) + quad) ^ (r16 & 7)) * 8;
#pragma unroll
    for (int i = 0; i < 4; ++i) {
      pA[h][i] = ldsA + (wy * 64 + i * 16 + r16) * BK + chunk;
      pB[h][i] = ldsB + (wx * 64 + i * 16 + r16) * BK + chunk;
    }
  }

#pragma unroll
  for (int i = 0; i < 4; ++i)
#pragma unroll
    for (int j = 0; j < 4; ++j)
      acc[i][j] = (floatx4){0.f, 0.f, 0.f, 0.f};

  for (int kt = 0; kt < kTiles; ++kt) {
#pragma unroll
    for (int is = 0; is < 4; ++is) {          // 4 issues x 32 rows = 128 rows
      gld_lds16(gA[is], la + is * (32 * BK));
      gld_lds16(gB[is], lb + is * (32 * BK));
      gA[is] += BK;
      gB[is] += BK;
    }
    __syncthreads();

#pragma unroll
    for (int h = 0; h < 2; ++h) {             // two K=32 halves per staged tile
      bf16x8 af[4], bfr[4];
#pragma unroll
      for (int i = 0; i < 4; ++i) af[i]  = *(const bf16x8*)pA[h][i];
#pragma unroll
      for (int j = 0; j < 4; ++j) bfr[j] = *(const bf16x8*)pB[h][j];
#pragma unroll
      for (int i = 0; i < 4; ++i)
#pragma unroll
        for (int j = 0; j < 4; ++j)
          acc[i][j] = __builtin_amdgcn_mfma_f32_16x16x32_bf16(af[i], bfr[j], acc[i][j], 0, 0, 0);
    }
    __syncthreads();
  }
}

#define EPILOGUE_SETUP()                       \
  const int t    = threadIdx.x;                \
  const int lane = t & 63;                     \
  const int wave = t >> 6;                     \
  const int wy   = wave >> 1;                  \
  const int wx   = wave & 1;                   \
  const int quad = lane >> 4;                  \
  const int r16  = lane & 15;

// ---------------- fused prep kernel ----------------
// blocks [0,4096): x fp32 -> bf16, 8 elems/thread; blocks [0,32) also zero rowsum
// blocks [4096,7168): transpose+cvt w_qkv [1024,3072] -> [3072,1024]
// blocks [7168,8192): transpose+cvt w_out [1024,1024] -> [1024,1024]
__global__ void __launch_bounds__(256) k_prep(
    const float* __restrict__ x, bf16_t* __restrict__ xb,
    const float* __restrict__ w_qkv, bf16_t* __restrict__ wqt,
    const float* __restrict__ w_out, bf16_t* __restrict__ wot,
    float* __restrict__ rowsum) {
  __shared__ float tile[32][33];
  const int bxk = blockIdx.x;
  const int t = threadIdx.x;
  if (bxk < 4096) {
    const size_t idx = (size_t)bxk * 256 + t;
    if (bxk < 32) rowsum[idx] = 0.0f;
    const float4 v0 = ((const float4*)x)[idx * 2];
    const float4 v1 = ((const float4*)x)[idx * 2 + 1];
    bf16x8 o;
    o[0] = (bf16_t)v0.x; o[1] = (bf16_t)v0.y; o[2] = (bf16_t)v0.z; o[3] = (bf16_t)v0.w;
    o[4] = (bf16_t)v1.x; o[5] = (bf16_t)v1.y; o[6] = (bf16_t)v1.z; o[7] = (bf16_t)v1.w;
    ((bf16x8*)xb)[idx] = o;
    return;
  }
  const bool first = bxk < 7168;
  const int tb = first ? (bxk - 4096) : (bxk - 7168);
  const float* in = first ? w_qkv : w_out;
  bf16_t* out = first ? wqt : wot;
  const int C = first ? 3072 : 1024;
  const int nCB = C >> 5;
  const int c0 = (tb % nCB) * 32;
  const int r0 = (tb / nCB) * 32;
  const int tx = t & 31, ty = t >> 5;
#pragma unroll
  for (int rr = 0; rr < 32; rr += 8)
    tile[ty + rr][tx] = in[(size_t)(r0 + ty + rr) * C + (c0 + tx)];
  __syncthreads();
#pragma unroll
  for (int cc = 0; cc < 32; cc += 8)
    out[(size_t)(c0 + ty + cc) * 1024 + (r0 + tx)] = (bf16_t)tile[tx][ty + cc];
}

// ---------------- GEMM kernels ----------------

// QKV: C[8192,3072] = Xb @ Wqkv_t^T. All three regions row-major now (V is no
// longer transposed — the VW GEMM consumes V row-major). Q pre-scaled 2^-5.
// Grid swizzled into 8-row super-bands for L2 locality on B.
__global__ void __launch_bounds__(256) k_gemm_qkv(
    const bf16_t* __restrict__ X, const bf16_t* __restrict__ Wt,
    bf16_t* __restrict__ Q, bf16_t* __restrict__ Kmat, bf16_t* __restrict__ V) {
  __shared__ bf16_t ldsA[BM * BK];
  __shared__ bf16_t ldsB[BN * BK];
  floatx4 acc[4][4];
  const int lin = blockIdx.y * 24 + blockIdx.x;
  const int st = lin / 192, r = lin % 192;
  const int by = st * 8 + (r & 7);
  const int bx = r >> 3;
  const int rowBase = by * BM;
  const int colBase = bx * BN;
  gemm_bt_core(X, 1024, Wt, 1024, rowBase, colBase, 1024 / BK, ldsA, ldsB, acc);
  EPILOGUE_SETUP();
  const int region = colBase >> 10;               // 0=Q 1=K 2=V (block-uniform)
  bf16_t* dst = region == 0 ? Q : (region == 1 ? Kmat : V);
  const float scale = region == 0 ? 0.03125f : 1.0f;   // fold softmax 1024^-0.5
  const int nb = colBase & 1023;
#pragma unroll
  for (int i = 0; i < 4; ++i) {
    const int m0 = rowBase + wy * 64 + i * 16 + quad * 4;
#pragma unroll
    for (int j = 0; j < 4; ++j) {
      const int n = nb + wx * 64 + j * 16 + r16;
#pragma unroll
      for (int rr = 0; rr < 4; ++rr)
        dst[(size_t)(m0 + rr) * 1024 + n] = (bf16_t)(acc[i][j][rr] * scale);
    }
  }
}

// QK^T + exp fused. Q pre-scaled so acc == logit (|logit| << 88, no max-sub).
// Writes p_unnorm bf16 (masked -> 0); fp32 row sums via quad-shfl + atomicAdd.
__global__ void __launch_bounds__(256) k_gemm_qk(
    const bf16_t* __restrict__ Q, const bf16_t* __restrict__ Kmat,
    bf16_t* __restrict__ P, float* __restrict__ rowsum) {
  const int lin = blockIdx.x;
  int by = (int)((sqrtf((float)(8 * lin + 1)) - 1.0f) * 0.5f);
  while ((by + 1) * (by + 2) / 2 <= lin) ++by;
  while (by * (by + 1) / 2 > lin) --by;
  const int bx = lin - by * (by + 1) / 2;
  const int b = blockIdx.z;

  __shared__ bf16_t ldsA[BM * BK];
  __shared__ bf16_t ldsB[BN * BK];
  floatx4 acc[4][4];
  const bf16_t* Ab = Q + (size_t)b * 2048 * 1024;
  const bf16_t* Bb = Kmat + (size_t)b * 2048 * 1024;
  const int rowBase = by * BM, colBase = bx * BN;
  gemm_bt_core(Ab, 1024, Bb, 1024, rowBase, colBase, 1024 / BK, ldsA, ldsB, acc);

  bf16_t* Pb = P + (size_t)b * 2048 * 2048;
  float* rs = rowsum + (size_t)b * 2048;
  EPILOGUE_SETUP();
  const bool offdiag = (bx < by);

  float partial[4][4];
#pragma unroll
  for (int i = 0; i < 4; ++i)
#pragma unroll
    for (int rr = 0; rr < 4; ++rr) partial[i][rr] = 0.f;

#pragma unroll
  for (int i = 0; i < 4; ++i) {
    const int m0 = rowBase + wy * 64 + i * 16 + quad * 4;
#pragma unroll
    for (int j = 0; j < 4; ++j) {
      const int n = colBase + wx * 64 + j * 16 + r16;
#pragma unroll
      for (int rr = 0; rr < 4; ++rr) {
        const int m = m0 + rr;
        const float e = (offdiag || n <= m) ? __expf(acc[i][j][rr]) : 0.0f;
        Pb[(size_t)m * 2048 + n] = (bf16_t)e;
        partial[i][rr] += e;
      }
    }
  }
#pragma unroll
  for (int i = 0; i < 4; ++i)
#pragma unroll
    for (int rr = 0; rr < 4; ++rr) {
      float v = partial[i][rr];
      v += __shfl_xor(v, 1, 64);
      v += __shfl_xor(v, 2, 64);
      v += __shfl_xor(v, 4, 64);
      v += __shfl_xor(v, 8, 64);
      partial[i][rr] = v;
    }
  if (r16 == 0) {
#pragma unroll
    for (int i = 0; i < 4; ++i) {
      const int m0 = rowBase + wy * 64 + i * 16 + quad * 4;
#pragma unroll
      for (int rr = 0; rr < 4; ++rr)
        atomicAdd(&rs[m0 + rr], partial[i][rr]);
    }
  }
}

// VW: VWt[b][n][s] = (V @ Wout^T)^T, bf16. A = V [8192,1024] row-major,
// Bt = wot [1024(n),1024(k)]. Epilogue scatters transposed (bf16x4 along s),
// mirroring the proven Vt scatter. Batch-independent row-wise GEMM.
__global__ void __launch_bounds__(256) k_gemm_vw(
    const bf16_t* __restrict__ V, const bf16_t* __restrict__ Wt,
    bf16_t* __restrict__ VWt) {
  __shared__ bf16_t ldsA[BM * BK];
  __shared__ bf16_t ldsB[BN * BK];
  floatx4 acc[4][4];
  const int rowBase = blockIdx.y * BM;
  const int colBase = blockIdx.x * BN;
  gemm_bt_core(V, 1024, Wt, 1024, rowBase, colBase, 1024 / BK, ldsA, ldsB, acc);
  EPILOGUE_SETUP();
  const int b = rowBase >> 11;                // 128-aligned rows: uniform batch
#pragma unroll
  for (int i = 0; i < 4; ++i) {
    const int m0 = rowBase + wy * 64 + i * 16 + quad * 4;
    const int s0 = m0 & 2047;
#pragma unroll
    for (int j = 0; j < 4; ++j) {
      const int n = colBase + wx * 64 + j * 16 + r16;
      bf16x4 pk;
#pragma unroll
      for (int rr = 0; rr < 4; ++rr) pk[rr] = (bf16_t)acc[i][j][rr];
      *(bf16x4*)(VWt + (size_t)(b * 1024 + n) * 2048 + s0) = pk;
    }
  }
}

// POVW: out[b][m][n] = (P_unnorm @ VWt^T) * inv_rowsum + bias, fp32.
// (P@V·inv)@W == (P@(V@W))·inv. Causal K-bound; heavy+light CU pairing:
// blocks l and l+256 get by = 15-u and by = u -> per-CU K-load balanced.
__global__ void __launch_bounds__(256) k_gemm_povw(
    const bf16_t* __restrict__ P, const bf16_t* __restrict__ VWt,
    const float* __restrict__ rowsum, const float* __restrict__ bias,
    float* __restrict__ out) {
  const int l = blockIdx.x;
  const int z = l >> 8;
  const int idx = l & 255;
  const int bx = idx & 7;
  const int u = (idx >> 3) & 7;
  const int b = idx >> 6;
  const int by = z ? u : (15 - u);

  __shared__ bf16_t ldsA[BM * BK];
  __shared__ bf16_t ldsB[BN * BK];
  floatx4 acc[4][4];
  const bf16_t* Ab = P + (size_t)b * 2048 * 2048;
  const bf16_t* Bb = VWt + (size_t)b * 1024 * 2048;
  const int rowBase = by * BM, colBase = bx * BN;
  gemm_bt_core(Ab, 2048, Bb, 2048, rowBase, colBase, (by + 1) * 2, ldsA, ldsB, acc);
  const float* rs = rowsum + (size_t)b * 2048;
  EPILOGUE_SETUP();
#pragma unroll
  for (int i = 0; i < 4; ++i) {
    const int m0 = rowBase + wy * 64 + i * 16 + quad * 4;
#pragma unroll
    for (int rr = 0; rr < 4; ++rr) {
      const float inv = 1.0f / rs[m0 + rr];
      const size_t row = (size_t)b * 2048 + m0 + rr;
#pragma unroll
      for (int j = 0; j < 4; ++j) {
        const int n = colBase + wx * 64 + j * 16 + r16;
        out[row * 1024 + n] = acc[i][j][rr] * inv + bias[n];
      }
    }
  }
}

// ---------------- launch ----------------
// ws layout (bytes):
//   xb     @ 0          16,777,216   x as bf16 [8192,1024]
//   wqkvt  @ 16777216    6,291,456   w_qkv^T bf16 [3072,1024]
//   woutt  @ 23068672    2,097,152   w_out^T bf16 [1024,1024]
//   q      @ 25165824   16,777,216   [b,s,1024] bf16 (pre-scaled by 2^-5)
//   k      @ 41943040   16,777,216   [b,s,1024] bf16
//   v      @ 58720256   16,777,216   [b,s,1024] bf16 row-major
//   rowsum @ 75497472       32,768   [b,s] fp32 sum of exp
//   p      @ 142606336  33,554,432   [b,s,s] bf16 unnormalized exp(logit)
//   vwt    @ 176160768  16,777,216   [b,1024(n),s] bf16 (V@Wout transposed)
extern "C" void kernel_launch(void* const* d_in, const int* in_sizes, int n_in,
                              void* d_out, int out_size, void* d_ws, size_t ws_size,
                              hipStream_t stream) {
  const float* x     = (const float*)d_in[0];
  const float* w_qkv = (const float*)d_in[1];
  const float* w_out = (const float*)d_in[2];
  const float* b_out = (const float*)d_in[3];
  float* out = (float*)d_out;
  char* ws = (char*)d_ws;

  bf16_t* xb     = (bf16_t*)(ws + 0);
  bf16_t* wqt    = (bf16_t*)(ws + 16777216);
  bf16_t* wot    = (bf16_t*)(ws + 23068672);
  bf16_t* q      = (bf16_t*)(ws + 25165824);
  bf16_t* kmat   = (bf16_t*)(ws + 41943040);
  bf16_t* v      = (bf16_t*)(ws + 58720256);
  float*  rowsum = (float*)(ws + 75497472);
  bf16_t* p      = (bf16_t*)(ws + 142606336);
  bf16_t* vwt    = (bf16_t*)(ws + 176160768);

  k_prep<<<8192, 256, 0, stream>>>(x, xb, w_qkv, wqt, w_out, wot, rowsum);
  k_gemm_qkv<<<dim3(24, 64), 256, 0, stream>>>(xb, wqt, q, kmat, v);
  k_gemm_vw<<<dim3(8, 64), 256, 0, stream>>>(v, wot, vwt);
  k_gemm_qk<<<dim3(136, 1, 4), 256, 0, stream>>>(q, kmat, p, rowsum);
  k_gemm_povw<<<512, 256, 0, stream>>>(p, vwt, rowsum, b_out, out);
}

// Round 7
// 254.568 us; speedup vs baseline: 1.3169x; 1.0515x over previous
//
#include <hip/hip_runtime.h>

typedef __bf16 bf16_t;
typedef __bf16 bf16x8 __attribute__((ext_vector_type(8)));
typedef __bf16 bf16x4 __attribute__((ext_vector_type(4)));
typedef float  floatx4 __attribute__((ext_vector_type(4)));

#define BM 128
#define BN 128
#define BK 64

// async global->LDS, 16B per lane. LDS dest is wave-uniform base + lane*16 (no
// scatter, no padding) — conflict-avoidance is done by permuting the GLOBAL
// chunk each lane fetches (XOR swizzle), not the LDS address.
__device__ __forceinline__ void gld_lds16(const bf16_t* g, bf16_t* l) {
  __builtin_amdgcn_global_load_lds(
      (__attribute__((address_space(1))) const void*)g,
      (__attribute__((address_space(3))) void*)l, 16, 0, 0);
}

// C[128x128] = A[M,K] @ Bt[N,K]^T tile. 256 threads = 4 waves in 2x2, each wave
// 64x64 via 4x4 mfma_f32_16x16x32_bf16. BK=64: 32 MFMA per barrier pair.
// LDS: row-major 128x64; chunk s of row r holds global chunk s^(r&7) -> frag
// ds_read_b128 is 2-way max (free). R5 form: inline addressing (84 VGPR);
// hoisting regressed occupancy (R6: 96 VGPR, -5%).
__device__ __forceinline__ void gemm_bt_core(
    const bf16_t* __restrict__ A, int lda,
    const bf16_t* __restrict__ Bt, int ldb,
    int rowBase, int colBase, int kTiles,   // kTiles counts BK=64 tiles
    bf16_t* ldsA, bf16_t* ldsB, floatx4 acc[4][4])
{
  const int t    = threadIdx.x;
  const int lane = t & 63;
  const int wave = t >> 6;
  const int wy   = wave >> 1;
  const int wx   = wave & 1;
  const int quad = lane >> 4;
  const int r16  = lane & 15;

  // staging: one issue = 256 lanes x 16B = 4KB = 32 rows of 128B
  const int srow   = t >> 3;                  // 0..31
  const int schunk = (t & 7) ^ (srow & 7);    // swizzled global chunk
  const bf16_t* ga = A  + (size_t)(rowBase + srow) * lda + schunk * 8;
  const bf16_t* gb = Bt + (size_t)(colBase + srow) * ldb + schunk * 8;
  bf16_t* la = ldsA + t * 8;                  // linear LDS, 16B per lane
  bf16_t* lb = ldsB + t * 8;

#pragma unroll
  for (int i = 0; i < 4; ++i)
#pragma unroll
    for (int j = 0; j < 4; ++j)
      acc[i][j] = (floatx4){0.f, 0.f, 0.f, 0.f};

  for (int kt = 0; kt < kTiles; ++kt) {
    const int k0 = kt * BK;
#pragma unroll
    for (int is = 0; is < 4; ++is) {          // 4 issues x 32 rows = 128 rows
      gld_lds16(ga + k0 + (size_t)(32 * is) * lda, la + is * (32 * BK));
      gld_lds16(gb + k0 + (size_t)(32 * is) * ldb, lb + is * (32 * BK));
    }
    __syncthreads();

#pragma unroll
    for (int h = 0; h < 2; ++h) {             // two K=32 halves per staged tile
      bf16x8 af[4], bfr[4];
#pragma unroll
      for (int i = 0; i < 4; ++i) {
        const int r = wy * 64 + i * 16 + r16;
        af[i] = *(const bf16x8*)(ldsA + r * BK + (((h << 2) + quad) ^ (r16 & 7)) * 8);
      }
#pragma unroll
      for (int j = 0; j < 4; ++j) {
        const int r = wx * 64 + j * 16 + r16;
        bfr[j] = *(const bf16x8*)(ldsB + r * BK + (((h << 2) + quad) ^ (r16 & 7)) * 8);
      }
#pragma unroll
      for (int i = 0; i < 4; ++i)
#pragma unroll
        for (int j = 0; j < 4; ++j)
          acc[i][j] = __builtin_amdgcn_mfma_f32_16x16x32_bf16(af[i], bfr[j], acc[i][j], 0, 0, 0);
    }
    __syncthreads();
  }
}

#define EPILOGUE_SETUP()                       \
  const int t    = threadIdx.x;                \
  const int lane = t & 63;                     \
  const int wave = t >> 6;                     \
  const int wy   = wave >> 1;                  \
  const int wx   = wave & 1;                   \
  const int quad = lane >> 4;                  \
  const int r16  = lane & 15;

// ---------------- fused prep kernel ----------------
// blocks [0,4096): x fp32 -> bf16, 8 elems/thread; blocks [0,32) also zero rowsum
// blocks [4096,7168): transpose+cvt w_qkv [1024,3072] -> [3072,1024]
// blocks [7168,8192): transpose+cvt w_out [1024,1024] -> [1024,1024]
__global__ void __launch_bounds__(256) k_prep(
    const float* __restrict__ x, bf16_t* __restrict__ xb,
    const float* __restrict__ w_qkv, bf16_t* __restrict__ wqt,
    const float* __restrict__ w_out, bf16_t* __restrict__ wot,
    float* __restrict__ rowsum) {
  __shared__ float tile[32][33];
  const int bxk = blockIdx.x;
  const int t = threadIdx.x;
  if (bxk < 4096) {
    const size_t idx = (size_t)bxk * 256 + t;
    if (bxk < 32) rowsum[idx] = 0.0f;
    const float4 v0 = ((const float4*)x)[idx * 2];
    const float4 v1 = ((const float4*)x)[idx * 2 + 1];
    bf16x8 o;
    o[0] = (bf16_t)v0.x; o[1] = (bf16_t)v0.y; o[2] = (bf16_t)v0.z; o[3] = (bf16_t)v0.w;
    o[4] = (bf16_t)v1.x; o[5] = (bf16_t)v1.y; o[6] = (bf16_t)v1.z; o[7] = (bf16_t)v1.w;
    ((bf16x8*)xb)[idx] = o;
    return;
  }
  const bool first = bxk < 7168;
  const int tb = first ? (bxk - 4096) : (bxk - 7168);
  const float* in = first ? w_qkv : w_out;
  bf16_t* out = first ? wqt : wot;
  const int C = first ? 3072 : 1024;
  const int nCB = C >> 5;
  const int c0 = (tb % nCB) * 32;
  const int r0 = (tb / nCB) * 32;
  const int tx = t & 31, ty = t >> 5;
#pragma unroll
  for (int rr = 0; rr < 32; rr += 8)
    tile[ty + rr][tx] = in[(size_t)(r0 + ty + rr) * C + (c0 + tx)];
  __syncthreads();
#pragma unroll
  for (int cc = 0; cc < 32; cc += 8)
    out[(size_t)(c0 + ty + cc) * 1024 + (r0 + tx)] = (bf16_t)tile[tx][ty + cc];
}

// ---------------- GEMM kernels ----------------

// QKV: C[8192,3072] = Xb @ Wqkv_t^T. Row-major Q (pre-scaled 2^-5), K, V.
// XCD-aware linear grid (1536): xcd = l&7 owns B col-blocks [3*xcd, 3*xcd+3)
// -> per-XCD B slice = 786 KB, resident in its private 4 MB L2.
__global__ void __launch_bounds__(256) k_gemm_qkv(
    const bf16_t* __restrict__ X, const bf16_t* __restrict__ Wt,
    bf16_t* __restrict__ Q, bf16_t* __restrict__ Kmat, bf16_t* __restrict__ V) {
  __shared__ bf16_t ldsA[BM * BK];
  __shared__ bf16_t ldsB[BN * BK];
  floatx4 acc[4][4];
  const int l = blockIdx.x;
  const int xcd = l & 7;
  const int s = l >> 3;               // 0..191
  const int bx = xcd * 3 + (s % 3);   // 0..23
  const int by = s / 3;               // 0..63
  const int rowBase = by * BM;
  const int colBase = bx * BN;
  gemm_bt_core(X, 1024, Wt, 1024, rowBase, colBase, 1024 / BK, ldsA, ldsB, acc);
  EPILOGUE_SETUP();
  const int region = colBase >> 10;               // 0=Q 1=K 2=V (block-uniform)
  bf16_t* dst = region == 0 ? Q : (region == 1 ? Kmat : V);
  const float scale = region == 0 ? 0.03125f : 1.0f;   // fold softmax 1024^-0.5
  const int nb = colBase & 1023;
#pragma unroll
  for (int i = 0; i < 4; ++i) {
    const int m0 = rowBase + wy * 64 + i * 16 + quad * 4;
#pragma unroll
    for (int j = 0; j < 4; ++j) {
      const int n = nb + wx * 64 + j * 16 + r16;
#pragma unroll
      for (int rr = 0; rr < 4; ++rr)
        dst[(size_t)(m0 + rr) * 1024 + n] = (bf16_t)(acc[i][j][rr] * scale);
    }
  }
}

// MID: merged QK^T+exp (blocks 0..543) and VW (blocks 544..1055). The two ops
// are mutually independent; one launch packs 4.1 blocks/CU so barrier drains
// and tails overlap.
__global__ void __launch_bounds__(256) k_mid(
    const bf16_t* __restrict__ Q, const bf16_t* __restrict__ Kmat,
    bf16_t* __restrict__ P, float* __restrict__ rowsum,
    const bf16_t* __restrict__ V, const bf16_t* __restrict__ Wt,
    bf16_t* __restrict__ VWt) {
  __shared__ bf16_t ldsA[BM * BK];
  __shared__ bf16_t ldsB[BN * BK];
  floatx4 acc[4][4];
  const int l = blockIdx.x;

  if (l < 544) {
    // ---- QK^T + exp. Q pre-scaled so acc == logit (|logit| << 88, no max-sub).
    const int b = l / 136;
    const int lin = l - 136 * b;
    int by = (int)((sqrtf((float)(8 * lin + 1)) - 1.0f) * 0.5f);
    while ((by + 1) * (by + 2) / 2 <= lin) ++by;
    while (by * (by + 1) / 2 > lin) --by;
    const int bx = lin - by * (by + 1) / 2;

    const bf16_t* Ab = Q + (size_t)b * 2048 * 1024;
    const bf16_t* Bb = Kmat + (size_t)b * 2048 * 1024;
    const int rowBase = by * BM, colBase = bx * BN;
    gemm_bt_core(Ab, 1024, Bb, 1024, rowBase, colBase, 1024 / BK, ldsA, ldsB, acc);

    bf16_t* Pb = P + (size_t)b * 2048 * 2048;
    float* rs = rowsum + (size_t)b * 2048;
    EPILOGUE_SETUP();
    const bool offdiag = (bx < by);

    float partial[4][4];
#pragma unroll
    for (int i = 0; i < 4; ++i)
#pragma unroll
      for (int rr = 0; rr < 4; ++rr) partial[i][rr] = 0.f;

#pragma unroll
    for (int i = 0; i < 4; ++i) {
      const int m0 = rowBase + wy * 64 + i * 16 + quad * 4;
#pragma unroll
      for (int j = 0; j < 4; ++j) {
        const int n = colBase + wx * 64 + j * 16 + r16;
#pragma unroll
        for (int rr = 0; rr < 4; ++rr) {
          const int m = m0 + rr;
          const float e = (offdiag || n <= m) ? __expf(acc[i][j][rr]) : 0.0f;
          Pb[(size_t)m * 2048 + n] = (bf16_t)e;
          partial[i][rr] += e;
        }
      }
    }
#pragma unroll
    for (int i = 0; i < 4; ++i)
#pragma unroll
      for (int rr = 0; rr < 4; ++rr) {
        float v = partial[i][rr];
        v += __shfl_xor(v, 1, 64);
        v += __shfl_xor(v, 2, 64);
        v += __shfl_xor(v, 4, 64);
        v += __shfl_xor(v, 8, 64);
        partial[i][rr] = v;
      }
    if (r16 == 0) {
#pragma unroll
      for (int i = 0; i < 4; ++i) {
        const int m0 = rowBase + wy * 64 + i * 16 + quad * 4;
#pragma unroll
        for (int rr = 0; rr < 4; ++rr)
          atomicAdd(&rs[m0 + rr], partial[i][rr]);
      }
    }
  } else {
    // ---- VW: VWt[b][n][s] = (V @ Wout^T)^T, bf16 (transposed scatter along s)
    const int t2 = l - 544;
    const int by = t2 >> 3, bx = t2 & 7;
    const int rowBase = by * BM, colBase = bx * BN;
    gemm_bt_core(V, 1024, Wt, 1024, rowBase, colBase, 1024 / BK, ldsA, ldsB, acc);
    EPILOGUE_SETUP();
    const int b = rowBase >> 11;              // 128-aligned rows: uniform batch
#pragma unroll
    for (int i = 0; i < 4; ++i) {
      const int m0 = rowBase + wy * 64 + i * 16 + quad * 4;
      const int s0 = m0 & 2047;
#pragma unroll
      for (int j = 0; j < 4; ++j) {
        const int n = colBase + wx * 64 + j * 16 + r16;
        bf16x4 pk;
#pragma unroll
        for (int rr = 0; rr < 4; ++rr) pk[rr] = (bf16_t)acc[i][j][rr];
        *(bf16x4*)(VWt + (size_t)(b * 1024 + n) * 2048 + s0) = pk;
      }
    }
  }
}

// POVW: out[b][m][n] = (P_unnorm @ VWt^T) * inv_rowsum + bias, fp32.
// (P@V·inv)@W == (P@(V@W))·inv. Causal K-bound; heavy+light CU pairing:
// blocks l and l+256 get by = 15-u and by = u -> per-CU K-load balanced.
__global__ void __launch_bounds__(256) k_gemm_povw(
    const bf16_t* __restrict__ P, const bf16_t* __restrict__ VWt,
    const float* __restrict__ rowsum, const float* __restrict__ bias,
    float* __restrict__ out) {
  const int l = blockIdx.x;
  const int z = l >> 8;
  const int idx = l & 255;
  const int bx = idx & 7;
  const int u = (idx >> 3) & 7;
  const int b = idx >> 6;
  const int by = z ? u : (15 - u);

  __shared__ bf16_t ldsA[BM * BK];
  __shared__ bf16_t ldsB[BN * BK];
  floatx4 acc[4][4];
  const bf16_t* Ab = P + (size_t)b * 2048 * 2048;
  const bf16_t* Bb = VWt + (size_t)b * 1024 * 2048;
  const int rowBase = by * BM, colBase = bx * BN;
  gemm_bt_core(Ab, 2048, Bb, 2048, rowBase, colBase, (by + 1) * 2, ldsA, ldsB, acc);
  const float* rs = rowsum + (size_t)b * 2048;
  EPILOGUE_SETUP();
#pragma unroll
  for (int i = 0; i < 4; ++i) {
    const int m0 = rowBase + wy * 64 + i * 16 + quad * 4;
#pragma unroll
    for (int rr = 0; rr < 4; ++rr) {
      const float inv = 1.0f / rs[m0 + rr];
      const size_t row = (size_t)b * 2048 + m0 + rr;
#pragma unroll
      for (int j = 0; j < 4; ++j) {
        const int n = colBase + wx * 64 + j * 16 + r16;
        out[row * 1024 + n] = acc[i][j][rr] * inv + bias[n];
      }
    }
  }
}

// ---------------- launch ----------------
// ws layout (bytes):
//   xb     @ 0          16,777,216   x as bf16 [8192,1024]
//   wqkvt  @ 16777216    6,291,456   w_qkv^T bf16 [3072,1024]
//   woutt  @ 23068672    2,097,152   w_out^T bf16 [1024,1024]
//   q      @ 25165824   16,777,216   [b,s,1024] bf16 (pre-scaled by 2^-5)
//   k      @ 41943040   16,777,216   [b,s,1024] bf16
//   v      @ 58720256   16,777,216   [b,s,1024] bf16 row-major
//   rowsum @ 75497472       32,768   [b,s] fp32 sum of exp
//   p      @ 142606336  33,554,432   [b,s,s] bf16 unnormalized exp(logit)
//   vwt    @ 176160768  16,777,216   [b,1024(n),s] bf16 (V@Wout transposed)
extern "C" void kernel_launch(void* const* d_in, const int* in_sizes, int n_in,
                              void* d_out, int out_size, void* d_ws, size_t ws_size,
                              hipStream_t stream) {
  const float* x     = (const float*)d_in[0];
  const float* w_qkv = (const float*)d_in[1];
  const float* w_out = (const float*)d_in[2];
  const float* b_out = (const float*)d_in[3];
  float* out = (float*)d_out;
  char* ws = (char*)d_ws;

  bf16_t* xb     = (bf16_t*)(ws + 0);
  bf16_t* wqt    = (bf16_t*)(ws + 16777216);
  bf16_t* wot    = (bf16_t*)(ws + 23068672);
  bf16_t* q      = (bf16_t*)(ws + 25165824);
  bf16_t* kmat   = (bf16_t*)(ws + 41943040);
  bf16_t* v      = (bf16_t*)(ws + 58720256);
  float*  rowsum = (float*)(ws + 75497472);
  bf16_t* p      = (bf16_t*)(ws + 142606336);
  bf16_t* vwt    = (bf16_t*)(ws + 176160768);

  k_prep<<<8192, 256, 0, stream>>>(x, xb, w_qkv, wqt, w_out, wot, rowsum);
  k_gemm_qkv<<<1536, 256, 0, stream>>>(xb, wqt, q, kmat, v);
  k_mid<<<1056, 256, 0, stream>>>(q, kmat, p, rowsum, v, wot, vwt);
  k_gemm_povw<<<512, 256, 0, stream>>>(p, vwt, rowsum, b_out, out);
}

// Round 8
// 244.955 us; speedup vs baseline: 1.3685x; 1.0392x over previous
//
#include <hip/hip_runtime.h>

typedef __bf16 bf16_t;
typedef __bf16 bf16x8 __attribute__((ext_vector_type(8)));
typedef __bf16 bf16x4 __attribute__((ext_vector_type(4)));
typedef float  floatx4 __attribute__((ext_vector_type(4)));

#define BM 128
#define BN 128
#define BK 64

// async global->LDS, 16B per lane. LDS dest is wave-uniform base + lane*16 (no
// scatter, no padding) — conflict-avoidance is done by permuting the GLOBAL
// chunk each lane fetches (XOR swizzle), not the LDS address.
__device__ __forceinline__ void gld_lds16(const bf16_t* g, bf16_t* l) {
  __builtin_amdgcn_global_load_lds(
      (__attribute__((address_space(1))) const void*)g,
      (__attribute__((address_space(3))) void*)l, 16, 0, 0);
}

// C[128x128] = A[M,K] @ Bt[N,K]^T tile. 256 threads = 4 waves in 2x2, each wave
// 64x64 via 4x4 mfma_f32_16x16x32_bf16. BK=64: 32 MFMA per barrier pair.
// LDS: row-major 128x64; chunk s of row r holds global chunk s^(r&7) -> frag
// ds_read_b128 is 2-way max (free). Inline addressing (84 VGPR); hoisting
// regressed occupancy (R6).
__device__ __forceinline__ void gemm_bt_core(
    const bf16_t* __restrict__ A, int lda,
    const bf16_t* __restrict__ Bt, int ldb,
    int rowBase, int colBase, int kTiles,   // kTiles counts BK=64 tiles
    bf16_t* ldsA, bf16_t* ldsB, floatx4 acc[4][4])
{
  const int t    = threadIdx.x;
  const int lane = t & 63;
  const int wave = t >> 6;
  const int wy   = wave >> 1;
  const int wx   = wave & 1;
  const int quad = lane >> 4;
  const int r16  = lane & 15;

  // staging: one issue = 256 lanes x 16B = 4KB = 32 rows of 128B
  const int srow   = t >> 3;                  // 0..31
  const int schunk = (t & 7) ^ (srow & 7);    // swizzled global chunk
  const bf16_t* ga = A  + (size_t)(rowBase + srow) * lda + schunk * 8;
  const bf16_t* gb = Bt + (size_t)(colBase + srow) * ldb + schunk * 8;
  bf16_t* la = ldsA + t * 8;                  // linear LDS, 16B per lane
  bf16_t* lb = ldsB + t * 8;

#pragma unroll
  for (int i = 0; i < 4; ++i)
#pragma unroll
    for (int j = 0; j < 4; ++j)
      acc[i][j] = (floatx4){0.f, 0.f, 0.f, 0.f};

  for (int kt = 0; kt < kTiles; ++kt) {
    const int k0 = kt * BK;
#pragma unroll
    for (int is = 0; is < 4; ++is) {          // 4 issues x 32 rows = 128 rows
      gld_lds16(ga + k0 + (size_t)(32 * is) * lda, la + is * (32 * BK));
      gld_lds16(gb + k0 + (size_t)(32 * is) * ldb, lb + is * (32 * BK));
    }
    __syncthreads();

#pragma unroll
    for (int h = 0; h < 2; ++h) {             // two K=32 halves per staged tile
      bf16x8 af[4], bfr[4];
#pragma unroll
      for (int i = 0; i < 4; ++i) {
        const int r = wy * 64 + i * 16 + r16;
        af[i] = *(const bf16x8*)(ldsA + r * BK + (((h << 2) + quad) ^ (r16 & 7)) * 8);
      }
#pragma unroll
      for (int j = 0; j < 4; ++j) {
        const int r = wx * 64 + j * 16 + r16;
        bfr[j] = *(const bf16x8*)(ldsB + r * BK + (((h << 2) + quad) ^ (r16 & 7)) * 8);
      }
#pragma unroll
      for (int i = 0; i < 4; ++i)
#pragma unroll
        for (int j = 0; j < 4; ++j)
          acc[i][j] = __builtin_amdgcn_mfma_f32_16x16x32_bf16(af[i], bfr[j], acc[i][j], 0, 0, 0);
    }
    __syncthreads();
  }
}

// 64x128 variant: BM=64, BN=128, waves 2x2 each 32x64, acc[2][4]. Same swizzle.
// Smaller tile -> 2x the blocks for occupancy-starved causal GEMMs (povw).
__device__ __forceinline__ void gemm_bt_core64(
    const bf16_t* __restrict__ A, int lda,
    const bf16_t* __restrict__ Bt, int ldb,
    int rowBase, int colBase, int kTiles,
    bf16_t* ldsA, bf16_t* ldsB, floatx4 acc[2][4])
{
  const int t    = threadIdx.x;
  const int lane = t & 63;
  const int wave = t >> 6;
  const int wy   = wave >> 1;      // 32-row half
  const int wx   = wave & 1;       // 64-col half
  const int quad = lane >> 4;
  const int r16  = lane & 15;

  const int srow   = t >> 3;
  const int schunk = (t & 7) ^ (srow & 7);
  const bf16_t* ga = A  + (size_t)(rowBase + srow) * lda + schunk * 8;
  const bf16_t* gb = Bt + (size_t)(colBase + srow) * ldb + schunk * 8;
  bf16_t* la = ldsA + t * 8;
  bf16_t* lb = ldsB + t * 8;

#pragma unroll
  for (int i = 0; i < 2; ++i)
#pragma unroll
    for (int j = 0; j < 4; ++j)
      acc[i][j] = (floatx4){0.f, 0.f, 0.f, 0.f};

  for (int kt = 0; kt < kTiles; ++kt) {
    const int k0 = kt * BK;
    gld_lds16(ga + k0,                    la);             // A: 64 rows = 2 issues
    gld_lds16(ga + k0 + (size_t)32 * lda, la + 32 * BK);
#pragma unroll
    for (int is = 0; is < 4; ++is)                         // B: 128 rows = 4 issues
      gld_lds16(gb + k0 + (size_t)(32 * is) * ldb, lb + is * (32 * BK));
    __syncthreads();

#pragma unroll
    for (int h = 0; h < 2; ++h) {
      bf16x8 af[2], bfr[4];
#pragma unroll
      for (int i = 0; i < 2; ++i) {
        const int r = wy * 32 + i * 16 + r16;
        af[i] = *(const bf16x8*)(ldsA + r * BK + (((h << 2) + quad) ^ (r16 & 7)) * 8);
      }
#pragma unroll
      for (int j = 0; j < 4; ++j) {
        const int r = wx * 64 + j * 16 + r16;
        bfr[j] = *(const bf16x8*)(ldsB + r * BK + (((h << 2) + quad) ^ (r16 & 7)) * 8);
      }
#pragma unroll
      for (int i = 0; i < 2; ++i)
#pragma unroll
        for (int j = 0; j < 4; ++j)
          acc[i][j] = __builtin_amdgcn_mfma_f32_16x16x32_bf16(af[i], bfr[j], acc[i][j], 0, 0, 0);
    }
    __syncthreads();
  }
}

#define EPILOGUE_SETUP()                       \
  const int t    = threadIdx.x;                \
  const int lane = t & 63;                     \
  const int wave = t >> 6;                     \
  const int wy   = wave >> 1;                  \
  const int wx   = wave & 1;                   \
  const int quad = lane >> 4;                  \
  const int r16  = lane & 15;

// ---------------- fused prep kernel ----------------
// blocks [0,4096): x fp32 -> bf16, 8 elems/thread; blocks [0,32) also zero rowsum
// blocks [4096,7168): transpose+cvt w_qkv [1024,3072] -> [3072,1024]
// blocks [7168,8192): transpose+cvt w_out [1024,1024] -> [1024,1024]
__global__ void __launch_bounds__(256) k_prep(
    const float* __restrict__ x, bf16_t* __restrict__ xb,
    const float* __restrict__ w_qkv, bf16_t* __restrict__ wqt,
    const float* __restrict__ w_out, bf16_t* __restrict__ wot,
    float* __restrict__ rowsum) {
  __shared__ float tile[32][33];
  const int bxk = blockIdx.x;
  const int t = threadIdx.x;
  if (bxk < 4096) {
    const size_t idx = (size_t)bxk * 256 + t;
    if (bxk < 32) rowsum[idx] = 0.0f;
    const float4 v0 = ((const float4*)x)[idx * 2];
    const float4 v1 = ((const float4*)x)[idx * 2 + 1];
    bf16x8 o;
    o[0] = (bf16_t)v0.x; o[1] = (bf16_t)v0.y; o[2] = (bf16_t)v0.z; o[3] = (bf16_t)v0.w;
    o[4] = (bf16_t)v1.x; o[5] = (bf16_t)v1.y; o[6] = (bf16_t)v1.z; o[7] = (bf16_t)v1.w;
    ((bf16x8*)xb)[idx] = o;
    return;
  }
  const bool first = bxk < 7168;
  const int tb = first ? (bxk - 4096) : (bxk - 7168);
  const float* in = first ? w_qkv : w_out;
  bf16_t* out = first ? wqt : wot;
  const int C = first ? 3072 : 1024;
  const int nCB = C >> 5;
  const int c0 = (tb % nCB) * 32;
  const int r0 = (tb / nCB) * 32;
  const int tx = t & 31, ty = t >> 5;
#pragma unroll
  for (int rr = 0; rr < 32; rr += 8)
    tile[ty + rr][tx] = in[(size_t)(r0 + ty + rr) * C + (c0 + tx)];
  __syncthreads();
#pragma unroll
  for (int cc = 0; cc < 32; cc += 8)
    out[(size_t)(c0 + ty + cc) * 1024 + (r0 + tx)] = (bf16_t)tile[tx][ty + cc];
}

// ---------------- GEMM kernels ----------------

// QKV: C[8192,3072] = Xb @ Wqkv_t^T. Row-major Q (pre-scaled 2^-5), K, V.
// XCD-aware linear grid (1536): xcd = l&7 owns B col-blocks [3*xcd, 3*xcd+3)
// -> per-XCD B slice = 786 KB, resident in its private 4 MB L2.
__global__ void __launch_bounds__(256) k_gemm_qkv(
    const bf16_t* __restrict__ X, const bf16_t* __restrict__ Wt,
    bf16_t* __restrict__ Q, bf16_t* __restrict__ Kmat, bf16_t* __restrict__ V) {
  __shared__ bf16_t ldsA[BM * BK];
  __shared__ bf16_t ldsB[BN * BK];
  floatx4 acc[4][4];
  const int l = blockIdx.x;
  const int xcd = l & 7;
  const int s = l >> 3;               // 0..191
  const int bx = xcd * 3 + (s % 3);   // 0..23
  const int by = s / 3;               // 0..63
  const int rowBase = by * BM;
  const int colBase = bx * BN;
  gemm_bt_core(X, 1024, Wt, 1024, rowBase, colBase, 1024 / BK, ldsA, ldsB, acc);
  EPILOGUE_SETUP();
  const int region = colBase >> 10;               // 0=Q 1=K 2=V (block-uniform)
  bf16_t* dst = region == 0 ? Q : (region == 1 ? Kmat : V);
  const float scale = region == 0 ? 0.03125f : 1.0f;   // fold softmax 1024^-0.5
  const int nb = colBase & 1023;
#pragma unroll
  for (int i = 0; i < 4; ++i) {
    const int m0 = rowBase + wy * 64 + i * 16 + quad * 4;
#pragma unroll
    for (int j = 0; j < 4; ++j) {
      const int n = nb + wx * 64 + j * 16 + r16;
#pragma unroll
      for (int rr = 0; rr < 4; ++rr)
        dst[(size_t)(m0 + rr) * 1024 + n] = (bf16_t)(acc[i][j][rr] * scale);
    }
  }
}

// MID: merged QK^T+exp (blocks 0..543) and VW (blocks 544..1055). The two ops
// are mutually independent; one launch packs ~4 blocks/CU so barrier drains
// and tails overlap.
__global__ void __launch_bounds__(256) k_mid(
    const bf16_t* __restrict__ Q, const bf16_t* __restrict__ Kmat,
    bf16_t* __restrict__ P, float* __restrict__ rowsum,
    const bf16_t* __restrict__ V, const bf16_t* __restrict__ Wt,
    bf16_t* __restrict__ VWt) {
  __shared__ bf16_t ldsA[BM * BK];
  __shared__ bf16_t ldsB[BN * BK];
  floatx4 acc[4][4];
  const int l = blockIdx.x;

  if (l < 544) {
    // ---- QK^T + exp. Q pre-scaled so acc == logit (|logit| << 88, no max-sub).
    const int b = l / 136;
    const int lin = l - 136 * b;
    int by = (int)((sqrtf((float)(8 * lin + 1)) - 1.0f) * 0.5f);
    while ((by + 1) * (by + 2) / 2 <= lin) ++by;
    while (by * (by + 1) / 2 > lin) --by;
    const int bx = lin - by * (by + 1) / 2;

    const bf16_t* Ab = Q + (size_t)b * 2048 * 1024;
    const bf16_t* Bb = Kmat + (size_t)b * 2048 * 1024;
    const int rowBase = by * BM, colBase = bx * BN;
    gemm_bt_core(Ab, 1024, Bb, 1024, rowBase, colBase, 1024 / BK, ldsA, ldsB, acc);

    bf16_t* Pb = P + (size_t)b * 2048 * 2048;
    float* rs = rowsum + (size_t)b * 2048;
    EPILOGUE_SETUP();
    const bool offdiag = (bx < by);

    float partial[4][4];
#pragma unroll
    for (int i = 0; i < 4; ++i)
#pragma unroll
      for (int rr = 0; rr < 4; ++rr) partial[i][rr] = 0.f;

#pragma unroll
    for (int i = 0; i < 4; ++i) {
      const int m0 = rowBase + wy * 64 + i * 16 + quad * 4;
#pragma unroll
      for (int j = 0; j < 4; ++j) {
        const int n = colBase + wx * 64 + j * 16 + r16;
#pragma unroll
        for (int rr = 0; rr < 4; ++rr) {
          const int m = m0 + rr;
          const float e = (offdiag || n <= m) ? __expf(acc[i][j][rr]) : 0.0f;
          Pb[(size_t)m * 2048 + n] = (bf16_t)e;
          partial[i][rr] += e;
        }
      }
    }
#pragma unroll
    for (int i = 0; i < 4; ++i)
#pragma unroll
      for (int rr = 0; rr < 4; ++rr) {
        float v = partial[i][rr];
        v += __shfl_xor(v, 1, 64);
        v += __shfl_xor(v, 2, 64);
        v += __shfl_xor(v, 4, 64);
        v += __shfl_xor(v, 8, 64);
        partial[i][rr] = v;
      }
    if (r16 == 0) {
#pragma unroll
      for (int i = 0; i < 4; ++i) {
        const int m0 = rowBase + wy * 64 + i * 16 + quad * 4;
#pragma unroll
        for (int rr = 0; rr < 4; ++rr)
          atomicAdd(&rs[m0 + rr], partial[i][rr]);
      }
    }
  } else {
    // ---- VW: VWt[b][n][s] = (V @ Wout^T)^T, bf16 (transposed scatter along s)
    const int t2 = l - 544;
    const int by = t2 >> 3, bx = t2 & 7;
    const int rowBase = by * BM, colBase = bx * BN;
    gemm_bt_core(V, 1024, Wt, 1024, rowBase, colBase, 1024 / BK, ldsA, ldsB, acc);
    EPILOGUE_SETUP();
    const int b = rowBase >> 11;              // 128-aligned rows: uniform batch
#pragma unroll
    for (int i = 0; i < 4; ++i) {
      const int m0 = rowBase + wy * 64 + i * 16 + quad * 4;
      const int s0 = m0 & 2047;
#pragma unroll
      for (int j = 0; j < 4; ++j) {
        const int n = colBase + wx * 64 + j * 16 + r16;
        bf16x4 pk;
#pragma unroll
        for (int rr = 0; rr < 4; ++rr) pk[rr] = (bf16_t)acc[i][j][rr];
        *(bf16x4*)(VWt + (size_t)(b * 1024 + n) * 2048 + s0) = pk;
      }
    }
  }
}

// POVW: out[b][m][n] = (P_unnorm @ VWt^T) * inv_rowsum + bias, fp32.
// 64x128 tiles: 1024 blocks = 4/CU, 16 waves/CU (vs 2/CU with 128-tiles —
// the R7 occupancy hole). Causal bound at 64-row granularity: ktiles = by'+1.
// Per-CU balance: blocks l, l+256, l+512, l+768 get by' = {31-w, w, 16+w, 15-w}
// -> 66 ktiles per CU, constant.
__global__ void __launch_bounds__(256) k_gemm_povw(
    const bf16_t* __restrict__ P, const bf16_t* __restrict__ VWt,
    const float* __restrict__ rowsum, const float* __restrict__ bias,
    float* __restrict__ out) {
  const int l = blockIdx.x;
  const int z = l >> 8;
  const int idx = l & 255;
  const int bx = idx & 7;
  const int w = (idx >> 3) & 7;
  const int b = idx >> 6;
  const int byp = (z == 0) ? (31 - w) : (z == 1) ? w : (z == 2) ? (16 + w) : (15 - w);

  __shared__ bf16_t ldsA[64 * BK];
  __shared__ bf16_t ldsB[BN * BK];
  floatx4 acc[2][4];
  const bf16_t* Ab = P + (size_t)b * 2048 * 2048;
  const bf16_t* Bb = VWt + (size_t)b * 1024 * 2048;
  const int rowBase = byp * 64, colBase = bx * BN;
  gemm_bt_core64(Ab, 2048, Bb, 2048, rowBase, colBase, byp + 1, ldsA, ldsB, acc);
  const float* rs = rowsum + (size_t)b * 2048;
  EPILOGUE_SETUP();
#pragma unroll
  for (int i = 0; i < 2; ++i) {
    const int m0 = rowBase + wy * 32 + i * 16 + quad * 4;
#pragma unroll
    for (int rr = 0; rr < 4; ++rr) {
      const float inv = 1.0f / rs[m0 + rr];
      const size_t row = (size_t)b * 2048 + m0 + rr;
#pragma unroll
      for (int j = 0; j < 4; ++j) {
        const int n = colBase + wx * 64 + j * 16 + r16;
        out[row * 1024 + n] = acc[i][j][rr] * inv + bias[n];
      }
    }
  }
}

// ---------------- launch ----------------
// ws layout (bytes):
//   xb     @ 0          16,777,216   x as bf16 [8192,1024]
//   wqkvt  @ 16777216    6,291,456   w_qkv^T bf16 [3072,1024]
//   woutt  @ 23068672    2,097,152   w_out^T bf16 [1024,1024]
//   q      @ 25165824   16,777,216   [b,s,1024] bf16 (pre-scaled by 2^-5)
//   k      @ 41943040   16,777,216   [b,s,1024] bf16
//   v      @ 58720256   16,777,216   [b,s,1024] bf16 row-major
//   rowsum @ 75497472       32,768   [b,s] fp32 sum of exp
//   p      @ 142606336  33,554,432   [b,s,s] bf16 unnormalized exp(logit)
//   vwt    @ 176160768  16,777,216   [b,1024(n),s] bf16 (V@Wout transposed)
extern "C" void kernel_launch(void* const* d_in, const int* in_sizes, int n_in,
                              void* d_out, int out_size, void* d_ws, size_t ws_size,
                              hipStream_t stream) {
  const float* x     = (const float*)d_in[0];
  const float* w_qkv = (const float*)d_in[1];
  const float* w_out = (const float*)d_in[2];
  const float* b_out = (const float*)d_in[3];
  float* out = (float*)d_out;
  char* ws = (char*)d_ws;

  bf16_t* xb     = (bf16_t*)(ws + 0);
  bf16_t* wqt    = (bf16_t*)(ws + 16777216);
  bf16_t* wot    = (bf16_t*)(ws + 23068672);
  bf16_t* q      = (bf16_t*)(ws + 25165824);
  bf16_t* kmat   = (bf16_t*)(ws + 41943040);
  bf16_t* v      = (bf16_t*)(ws + 58720256);
  float*  rowsum = (float*)(ws + 75497472);
  bf16_t* p      = (bf16_t*)(ws + 142606336);
  bf16_t* vwt    = (bf16_t*)(ws + 176160768);

  k_prep<<<8192, 256, 0, stream>>>(x, xb, w_qkv, wqt, w_out, wot, rowsum);
  k_gemm_qkv<<<1536, 256, 0, stream>>>(xb, wqt, q, kmat, v);
  k_mid<<<1056, 256, 0, stream>>>(q, kmat, p, rowsum, v, wot, vwt);
  k_gemm_povw<<<1024, 256, 0, stream>>>(p, vwt, rowsum, b_out, out);
}